// Round 10
// baseline (930.266 us; speedup 1.0000x reference)
//
#include <hip/hip_runtime.h>
#include <stdint.h>

#define LEAKY 0.1f
typedef unsigned short u16;
typedef unsigned int u32;
typedef unsigned char u8;
typedef short bf16x8 __attribute__((ext_vector_type(8)));
typedef float f32x4 __attribute__((ext_vector_type(4)));

// ---------- bf16 helpers (storage = ushort) ----------
__device__ __forceinline__ float bflo(u32 u){ union{u32 i; float f;} c; c.i = u<<16; return c.f; }
__device__ __forceinline__ float bfhi(u32 u){ union{u32 i; float f;} c; c.i = u & 0xffff0000u; return c.f; }
__device__ __forceinline__ float bf2f(u16 v){ union{u32 i; float f;} c; c.i = ((u32)v)<<16; return c.f; }
__device__ __forceinline__ u16 f2bf(float f){
  union{float f; u32 i;} c; c.f = f;
  u32 r = (c.i + 0x7fffu + ((c.i>>16)&1u)) >> 16;
  return (u16)r;
}
__device__ __forceinline__ u32 pack2(float a, float b){ return (u32)f2bf(a) | ((u32)f2bf(b)<<16); }

// ---------- fp8 e4m3fn helpers (r9: Y gather payload compression) ----------
// decode: value = as_float(em<<20) * 2^120 (exact, incl. subnormals); sign or'd.
__device__ __forceinline__ float fp8_to_f(u32 b){
  union{u32 i; float f;} c; c.i = (b & 0x7fu) << 20;
  union{float f; u32 i;} o; o.f = c.f * 0x1p+120f;
  o.i |= (b & 0x80u) << 24;
  return o.f;
}
// encode: |f|*2^-120 re-biases exponent; round-to-nearest-even at bit 20.
__device__ __forceinline__ u32 f2fp8(float f){
  union{float f; u32 i;} c; c.f = f;
  u32 s = (c.i >> 24) & 0x80u;
  float a = fabsf(f); if (a > 448.f) a = 448.f;
  union{float f; u32 i;} d; d.f = a * 0x1p-120f;
  u32 u = d.i;
  u32 r = (u + 0x7FFFFu + ((u >> 20) & 1u)) >> 20;
  if (r > 0x7Eu) r = 0x7Eu;
  return s | r;
}

__device__ __forceinline__ void load8f(const float* p, float* v){
  const float4* q = (const float4*)p; float4 a = q[0], b = q[1];
  v[0]=a.x;v[1]=a.y;v[2]=a.z;v[3]=a.w;v[4]=b.x;v[5]=b.y;v[6]=b.z;v[7]=b.w;
}
__device__ __forceinline__ void load8h(const u16* p, float* v){
  uint4 u = *(const uint4*)p;
  v[0]=bflo(u.x);v[1]=bfhi(u.x);v[2]=bflo(u.y);v[3]=bfhi(u.y);
  v[4]=bflo(u.z);v[5]=bfhi(u.z);v[6]=bflo(u.w);v[7]=bfhi(u.w);
}
__device__ __forceinline__ void load4f(const float* p, float* v){
  float4 a = *(const float4*)p; v[0]=a.x;v[1]=a.y;v[2]=a.z;v[3]=a.w;
}
__device__ __forceinline__ void load4h(const u16* p, float* v){
  uint2 u = *(const uint2*)p;
  v[0]=bflo(u.x); v[1]=bfhi(u.x); v[2]=bflo(u.y); v[3]=bfhi(u.y);
}
__device__ __forceinline__ void store2bf(u16* p, float a, float b){
  *(u32*)p = pack2(a,b);
}
__device__ __forceinline__ void store4bf(u16* p, float a, float b, float c, float d){
  uint2 t; t.x = pack2(a,b); t.y = pack2(c,d);
  *(uint2*)p = t;
}

// ---------- misc: zero an int buffer ----------
__global__ __launch_bounds__(256) void zero_kernel(int* p, int n){
  int i = blockIdx.x*256 + threadIdx.x;
  if (i < n) p[i] = 0;
}

// ---------- stage W[128][128] fp32 -> LDS transposed bf16 Wt[n][k], stride 136 ----------
__device__ __forceinline__ void stageWt(const float* __restrict__ W, u16* Wt, int tid){
  const int n = tid & 127, khalf = tid >> 7;
#pragma unroll
  for (int g = 0; g < 16; ++g) {
    int k0 = khalf*64 + g*4;
    float w0 = W[(k0+0)*128 + n];
    float w1 = W[(k0+1)*128 + n];
    float w2 = W[(k0+2)*128 + n];
    float w3 = W[(k0+3)*128 + n];
    uint2 t; t.x = pack2(w0,w1); t.y = pack2(w2,w3);
    *(uint2*)&Wt[n*136 + k0] = t;
  }
}

// ---------- MFMA GEMM core: C[N,128] = A[N,128] @ W[128,128] ----------
// Output: bf16 (C) or fp8 e4m3 (C8, when non-null -- Y gather payload).
__device__ __forceinline__ void gemm_core(
    const float* __restrict__ Af, const u16* __restrict__ Ah,
    const float* __restrict__ W, u16* __restrict__ C, u8* __restrict__ C8,
    int N, int brow, u16* Wt, int tid)
{
  stageWt(W, Wt, tid);
  __syncthreads();

  const int w = tid >> 6, lane = tid & 63;
  const int m = lane & 15, quad = lane >> 4;
  const int rowBase = brow*64 + w*16;
  int arow = rowBase + m;
  if (arow >= N) arow = N-1;

  bf16x8 af[4];
  if (Ah) {
#pragma unroll
    for (int kt=0; kt<4; ++kt)
      af[kt] = *(const bf16x8*)(Ah + (size_t)arow*128 + kt*32 + quad*8);
  } else {
#pragma unroll
    for (int kt=0; kt<4; ++kt) {
      float v[8]; load8f(Af + (size_t)arow*128 + kt*32 + quad*8, v);
      bf16x8 t;
#pragma unroll
      for (int j=0;j<8;++j) t[j] = (short)f2bf(v[j]);
      af[kt] = t;
    }
  }

#pragma unroll
  for (int jt=0; jt<8; ++jt) {
    f32x4 acc = {0.f,0.f,0.f,0.f};
#pragma unroll
    for (int kt=0; kt<4; ++kt) {
      bf16x8 bf = *(const bf16x8*)&Wt[(jt*16+m)*136 + kt*32 + quad*8];
      acc = __builtin_amdgcn_mfma_f32_16x16x32_bf16(af[kt], bf, acc, 0, 0, 0);
    }
    const int col = jt*16 + m;
#pragma unroll
    for (int r=0;r<4;++r) {
      int rg = rowBase + quad*4 + r;
      if (rg < N) {
        if (C8) C8[(size_t)rg*128 + col] = (u8)f2fp8(acc[r]);
        else    C[(size_t)rg*128 + col] = f2bf(acc[r]);
      }
    }
  }
}

// dual GEMM: blocks [0,g1) -> side1, rest -> side2
__global__ __launch_bounds__(256) void gemm128_dual(
    const float* Af1, const u16* Ah1, const float* W1, u16* C1, u8* C81, int N1, int g1,
    const float* Af2, const u16* Ah2, const float* W2, u16* C2, u8* C82, int N2)
{
  __shared__ alignas(16) u16 Wt[128*136];
  const int b = blockIdx.x;
  if (b < g1) gemm_core(Af1, Ah1, W1, C1, C81, N1, b,      Wt, threadIdx.x);
  else        gemm_core(Af2, Ah2, W2, C2, C82, N2, b - g1, Wt, threadIdx.x);
}

// dual update kernel
__global__ __launch_bounds__(256) void update_dual(
    const u16* T1, const u16* Hy1, const float* W1,
    const float* PF1, const u16* PH1, u16* Po1, float* S1, int N1, int g1,
    const u16* T2, const u16* Hy2, const float* W2,
    const float* PF2, const u16* PH2, u16* Po2, float* S2, int N2, int initS)
{
  __shared__ alignas(16) char shmem[34816];  // union: Wt u16[128*136] | Gs f32[64*132]
  u16* Wt = (u16*)shmem;
  float* Gs = (float*)shmem;
  const int tid = threadIdx.x;
  const int b = blockIdx.x;

  const u16* T; const u16* Hy; const float* latW;
  const float* PrevF; const u16* PrevH; u16* Pout; float* S; int N; int brow;
  if (b < g1) { T=T1; Hy=Hy1; latW=W1; PrevF=PF1; PrevH=PH1; Pout=Po1; S=S1; N=N1; brow=b; }
  else        { T=T2; Hy=Hy2; latW=W2; PrevF=PF2; PrevH=PH2; Pout=Po2; S=S2; N=N2; brow=b-g1; }

  stageWt(latW, Wt, tid);
  __syncthreads();

  const int w = tid >> 6, lane = tid & 63;
  const int m = lane & 15, quad = lane >> 4;
  const int rowBase = brow*64;
  int arow = rowBase + w*16 + m;
  if (arow >= N) arow = N-1;

  bf16x8 af[4];
#pragma unroll
  for (int kt=0; kt<4; ++kt)
    af[kt] = *(const bf16x8*)(Hy + (size_t)arow*128 + kt*32 + quad*8);

  f32x4 acc[8];
#pragma unroll
  for (int jt=0; jt<8; ++jt) {
    f32x4 a = {0.f,0.f,0.f,0.f};
#pragma unroll
    for (int kt=0; kt<4; ++kt) {
      bf16x8 bf = *(const bf16x8*)&Wt[(jt*16+m)*136 + kt*32 + quad*8];
      a = __builtin_amdgcn_mfma_f32_16x16x32_bf16(af[kt], bf, a, 0, 0, 0);
    }
    acc[jt] = a;
  }
  __syncthreads();   // all Wt reads done; reuse LDS as Gs
#pragma unroll
  for (int jt=0; jt<8; ++jt) {
#pragma unroll
    for (int r=0;r<4;++r) {
      float x = acc[jt][r];
      Gs[(w*16 + quad*4 + r)*132 + jt*16 + m] = x > 0.f ? x : LEAKY*x;
    }
  }
  __syncthreads();

  const int c4 = (tid & 31) * 4;
  const int r0 = tid >> 5;
#pragma unroll
  for (int ri=0; ri<8; ++ri) {
    int lr = r0 + ri*8;           // 0..63
    int n = rowBase + lr;
    if (n >= N) continue;
    size_t off = (size_t)n*128 + c4;
    float gv[4]; load4f(&Gs[lr*132 + c4], gv);
    float tv[4], pv[4], ov[4];
    load4h(T + off, tv);
    if (PrevH) load4h(PrevH + off, pv);
    else       load4f(PrevF + off, pv);
#pragma unroll
    for (int cc=0;cc<4;++cc) ov[cc] = gv[cc] + tv[cc] + pv[cc];
    if (Pout)
      store4bf(&Pout[off], ov[0],ov[1],ov[2],ov[3]);
    if (initS) {
      float4 s; s.x=pv[0]+ov[0]; s.y=pv[1]+ov[1]; s.z=pv[2]+ov[2]; s.w=pv[3]+ov[3];
      *(float4*)&S[off] = s;
    } else {
      float4 s = *(const float4*)&S[off];
      s.x += ov[0]; s.y += ov[1]; s.z += ov[2]; s.w += ov[3];
      *(float4*)&S[off] = s;
    }
  }
}

// ---------- hyper reduce v2 (MFMA): part[b] = Hy_chunk^T @ Lat_chunk ----------
// r5: VALU version was 89.7us with MfmaUtil=0, VALUBusy=50% -- a 4.9 GFLOP
// matmul on the scalar pipe. MFMA-ized; r6: 89.7 -> off top-5.
#define RPAD 40
__global__ __launch_bounds__(256) void reduce_kernel(
    const u16* __restrict__ HyU, const u16* __restrict__ HyI,
    const float* __restrict__ LatUf, const u16* __restrict__ LatUh,
    const float* __restrict__ LatIf, const u16* __restrict__ LatIh,
    u16* __restrict__ part, int Nu, int Ni, int nbU)
{
  __shared__ alignas(16) u16 HsT[128*RPAD];
  __shared__ alignas(16) u16 LsT[128*RPAD];
  const int b = blockIdx.x;
  const u16* Hy; const float* Lf; const u16* Lh; int N, cstart;
  if (b < nbU) { Hy=HyU; Lf=LatUf; Lh=LatUh; N=Nu; cstart = b*256; }
  else         { Hy=HyI; Lf=LatIf; Lh=LatIh; N=Ni; cstart = (b-nbU)*256; }
  const int cend = (N < cstart+256) ? N : (cstart+256);
  const int tid = threadIdx.x;
  const int w = tid >> 6, lane = tid & 63;
  const int m = lane & 15, quad = lane >> 4;

  f32x4 acc[2][8];
#pragma unroll
  for (int a=0;a<2;++a)
#pragma unroll
    for (int c=0;c<8;++c) { acc[a][c][0]=0.f; acc[a][c][1]=0.f; acc[a][c][2]=0.f; acc[a][c][3]=0.f; }

  for (int t0 = cstart; t0 < cend; t0 += 32) {
#pragma unroll
    for (int it=0; it<2; ++it) {
      const int idx = it*256 + tid;
      const int n = idx & 31, h0 = (idx >> 5) * 8;
      const int row = t0 + n;
      u32 ax=0, ay=0, az=0, aw=0, lx=0, ly=0, lz=0, lw=0;
      if (row < cend) {
        uint4 uh = *(const uint4*)(Hy + (size_t)row*128 + h0);
        ax=uh.x; ay=uh.y; az=uh.z; aw=uh.w;
        if (Lh) {
          uint4 ul = *(const uint4*)(Lh + (size_t)row*128 + h0);
          lx=ul.x; ly=ul.y; lz=ul.z; lw=ul.w;
        } else {
          float v[8]; load8f(Lf + (size_t)row*128 + h0, v);
          lx = pack2(v[0],v[1]); ly = pack2(v[2],v[3]);
          lz = pack2(v[4],v[5]); lw = pack2(v[6],v[7]);
        }
      }
      u16* hp = &HsT[h0*RPAD + n];
      hp[0*RPAD]=(u16)ax; hp[1*RPAD]=(u16)(ax>>16);
      hp[2*RPAD]=(u16)ay; hp[3*RPAD]=(u16)(ay>>16);
      hp[4*RPAD]=(u16)az; hp[5*RPAD]=(u16)(az>>16);
      hp[6*RPAD]=(u16)aw; hp[7*RPAD]=(u16)(aw>>16);
      u16* lp = &LsT[h0*RPAD + n];
      lp[0*RPAD]=(u16)lx; lp[1*RPAD]=(u16)(lx>>16);
      lp[2*RPAD]=(u16)ly; lp[3*RPAD]=(u16)(ly>>16);
      lp[4*RPAD]=(u16)lz; lp[5*RPAD]=(u16)(lz>>16);
      lp[6*RPAD]=(u16)lw; lp[7*RPAD]=(u16)(lw>>16);
    }
    __syncthreads();
    bf16x8 a0 = *(const bf16x8*)&HsT[(w*32 +      m)*RPAD + quad*8];
    bf16x8 a1 = *(const bf16x8*)&HsT[(w*32 + 16 + m)*RPAD + quad*8];
#pragma unroll
    for (int td=0; td<8; ++td) {
      bf16x8 bfr = *(const bf16x8*)&LsT[(td*16 + m)*RPAD + quad*8];
      acc[0][td] = __builtin_amdgcn_mfma_f32_16x16x32_bf16(a0, bfr, acc[0][td], 0, 0, 0);
      acc[1][td] = __builtin_amdgcn_mfma_f32_16x16x32_bf16(a1, bfr, acc[1][td], 0, 0, 0);
    }
    __syncthreads();
  }
  u16* pb = part + (size_t)b*16384;
#pragma unroll
  for (int th=0; th<2; ++th) {
    const int h = w*32 + th*16 + quad*4;
#pragma unroll
    for (int td=0; td<8; ++td) {
      const int d = td*16 + m;
#pragma unroll
      for (int r=0;r<4;++r)
        pb[(size_t)(h+r)*128 + d] = f2bf(acc[th][td][r]);
    }
  }
}

// ---------- 2-stage partial reduction (r4: single-stage was 93us at 4%
// occupancy -- 391 serial strided loads/thread, latency-bound) ----------
#define JS 16
__global__ __launch_bounds__(256) void reduce2a_kernel(
    const u16* __restrict__ part, float* __restrict__ Rp,
    int nbU, int nbI)
{
  const int e = blockIdx.x*256 + threadIdx.x;   // 0..16383
  const int side = blockIdx.z;
  const int nb = side ? nbI : nbU;
  const int per = (nb + JS - 1) / JS;
  const int j0 = blockIdx.y * per;
  int j1 = j0 + per; if (j1 > nb) j1 = nb;
  const u16* p = part + (side ? (size_t)nbU*16384 : 0) + e;
  float s = 0.f;
  for (int j=j0; j<j1; ++j) s += bf2f(p[(size_t)j*16384]);
  Rp[((size_t)side*JS + blockIdx.y)*16384 + e] = s;
}

__global__ __launch_bounds__(256) void reduce2b_kernel(
    const float* __restrict__ Rp, float* __restrict__ Ru, float* __restrict__ Ri)
{
  const int e = blockIdx.x*256 + threadIdx.x;   // 0..16383
  const int side = blockIdx.y;
  const float* p = Rp + (size_t)side*JS*16384 + e;
  float s = 0.f;
#pragma unroll
  for (int j=0; j<JS; ++j) s += p[(size_t)j*16384];
  if (side) Ri[e] = s; else Ru[e] = s;
}

// ---------- FC chain ----------
__global__ __launch_bounds__(128) void fc_kernel(
    const float* __restrict__ Ru, const float* __restrict__ Ri,
    const float* __restrict__ W3u, const float* __restrict__ W3i,
    float* __restrict__ latU, float* __restrict__ latI)
{
  __shared__ float cur[128];
  const int h = threadIdx.x;
  const int d = blockIdx.x;
  const int side = blockIdx.y;
  const float* R  = side ? Ri  : Ru;
  const float* W3 = side ? W3i : W3u;
  float* lat      = side ? latI : latU;
  float x = R[h*128 + d];
  cur[h] = x > 0.f ? x : LEAKY*x;
  __syncthreads();
  for (int s=0;s<3;++s) {
    const float* w = W3 + s*16384 + h;
    float val = 0.f;
#pragma unroll 8
    for (int hp=0; hp<128; ++hp) val = fmaf(cur[hp], w[hp*128], val);
    val = (val > 0.f ? val : 0.f) + cur[h];
    __syncthreads();
    cur[h] = val;
    __syncthreads();
  }
  lat[h*128+d] = cur[h];
}

// ---------- CSR-based SpMM: T[row,:] = relu( sum_e val_e * Y[idx_e,:] ) ----------
// r9: Y payload is fp8 e4m3 (128B/row = 1 cache line). r8 proved the bound is
// L3 line throughput / replication (MLP doubling failed; FETCH invariant at
// 154MB vs the 8-XCD x 12.8MB = 102MB replication floor). Halving lines per
// edge is the only lever on a uniform-random graph. Decode: 4 VALU ops/elem.
__global__ __launch_bounds__(256) void spmm_kernel(
    const uint2* __restrict__ csr, const int* __restrict__ rowptr,
    const u8* __restrict__ Y, u16* __restrict__ T, int N, int Ncol, int E)
{
  const int lane = threadIdx.x & 63;
  const int row = blockIdx.x*4 + (threadIdx.x >> 6);
  if (row >= N) return;
  int e  = rowptr[row];
  int e1 = rowptr[row+1];
  if (e < 0) e = 0;
  if (e > E) e = E;
  if (e1 < e) e1 = e;
  if (e1 > E) e1 = E;
  const u32 cmax = (u32)(Ncol - 1);
  float a0=0.f, a1=0.f;
  const int c2 = lane*2;
  for (; e+4 <= e1; e += 4) {
    uint2 p0 = csr[e], p1 = csr[e+1], p2 = csr[e+2], p3 = csr[e+3];
    u32 i0 = p0.x < cmax ? p0.x : cmax;
    u32 i1 = p1.x < cmax ? p1.x : cmax;
    u32 i2 = p2.x < cmax ? p2.x : cmax;
    u32 i3 = p3.x < cmax ? p3.x : cmax;
    u32 y0 = *(const u16*)&Y[(size_t)i0*128 + c2];
    u32 y1 = *(const u16*)&Y[(size_t)i1*128 + c2];
    u32 y2 = *(const u16*)&Y[(size_t)i2*128 + c2];
    u32 y3 = *(const u16*)&Y[(size_t)i3*128 + c2];
    float v0 = __uint_as_float(p0.y), v1 = __uint_as_float(p1.y);
    float v2 = __uint_as_float(p2.y), v3 = __uint_as_float(p3.y);
    a0 = fmaf(v0, fp8_to_f(y0 & 0xffu), a0); a1 = fmaf(v0, fp8_to_f(y0 >> 8), a1);
    a0 = fmaf(v1, fp8_to_f(y1 & 0xffu), a0); a1 = fmaf(v1, fp8_to_f(y1 >> 8), a1);
    a0 = fmaf(v2, fp8_to_f(y2 & 0xffu), a0); a1 = fmaf(v2, fp8_to_f(y2 >> 8), a1);
    a0 = fmaf(v3, fp8_to_f(y3 & 0xffu), a0); a1 = fmaf(v3, fp8_to_f(y3 >> 8), a1);
  }
  for (; e < e1; ++e) {
    uint2 p0 = csr[e];
    u32 i0 = p0.x < cmax ? p0.x : cmax;
    u32 y0 = *(const u16*)&Y[(size_t)i0*128 + c2];
    float v0 = __uint_as_float(p0.y);
    a0 = fmaf(v0, fp8_to_f(y0 & 0xffu), a0); a1 = fmaf(v0, fp8_to_f(y0 >> 8), a1);
  }
  store2bf(&T[(size_t)row*128 + c2], a0 > 0.f ? a0 : 0.f, a1 > 0.f ? a1 : 0.f);
}

// ---------- CSR build ----------
// hist v3: zero global atomics (r2/r3: memory-side atomics cost ~31B write
// each, any scope) AND full-chip parallelism (r3 failure: 176 blocks = 7%
// occupancy, latency-bound at 179us). u16-packed LDS bins double bins/KB:
// 32768 bins per 64KB chunk -> 6 chunks (4 U + 2 I); HS=64 edge slices ->
// 384 blocks. Overflow-safe by construction: per-slice count <= per = 25000
// < 65536. int4 key loads cut loop trips 4x. Partial = 24.6MB, aliases
// csrU+csrI (both free until scatter, stream-ordered).
#define HCB 32768              // bins per chunk (u16-packed)
#define HWORDS (HCB/2)         // 16384 u32 words = 64KB
#define HS  64                 // edge slices
__global__ __launch_bounds__(256) void hist_part_kernel(
    const int* __restrict__ rows, const int* __restrict__ cols,
    u32* __restrict__ part, int E, int cU)
{
  __shared__ alignas(16) u32 h[HWORDS];
  const int c = blockIdx.x, s = blockIdx.y;
  const int* key = (c < cU) ? rows : cols;
  const u32 lo = (u32)((c < cU ? c : c - cU) * HCB);
  {
    uint4 z; z.x=0; z.y=0; z.z=0; z.w=0;
    uint4* h4 = (uint4*)h;
    for (int i = threadIdx.x; i < HWORDS/4; i += 256) h4[i] = z;
  }
  __syncthreads();
  int per = (E + HS - 1) / HS;
  per = (per + 3) & ~3;                      // multiple of 4: int4-aligned slices
  const int e0 = s*per;
  const int e1 = (E < e0+per) ? E : (e0+per);
  if (e0 < e1) {
    const int4* kp = (const int4*)(key + e0);
    const int nv = (e1 - e0) >> 2;
    for (int i = threadIdx.x; i < nv; i += 256) {
      int4 kv = kp[i];
      u32 k0=(u32)kv.x-lo, k1=(u32)kv.y-lo, k2=(u32)kv.z-lo, k3=(u32)kv.w-lo;
      if (k0 < (u32)HCB) atomicAdd(&h[k0>>1], 1u << ((k0&1)<<4));
      if (k1 < (u32)HCB) atomicAdd(&h[k1>>1], 1u << ((k1&1)<<4));
      if (k2 < (u32)HCB) atomicAdd(&h[k2>>1], 1u << ((k2&1)<<4));
      if (k3 < (u32)HCB) atomicAdd(&h[k3>>1], 1u << ((k3&1)<<4));
    }
    for (int e = e0 + (nv<<2) + threadIdx.x; e < e1; e += 256) {
      u32 k = (u32)key[e] - lo;
      if (k < (u32)HCB) atomicAdd(&h[k>>1], 1u << ((k&1)<<4));
    }
  }
  __syncthreads();
  uint4* dst = (uint4*)(part + (size_t)(c*HS + s) * HWORDS);
  const uint4* h4 = (const uint4*)h;
  for (int i = threadIdx.x; i < HWORDS/4; i += 256) dst[i] = h4[i];
}

__global__ __launch_bounds__(256) void scan_local_kernel(
    const u32* __restrict__ part,
    int* rpU, int* rpI, int* bsU, int* bsI, int Nu, int Ni, int cU)
{
  const int side = blockIdx.y;
  const int Nn = side ? Ni : Nu;
  int* rp = side ? rpI : rpU;
  int* bs = side ? bsI : bsU;
  const int nb = (Nn + 4095) >> 12;
  if ((int)blockIdx.x >= nb) return;
  __shared__ int sa[256], sb[256];
  const int tid = threadIdx.x;
  const int base = blockIdx.x*4096 + tid*16;   // 16 bins; never crosses a 32768 chunk boundary
  int v[16];
#pragma unroll
  for (int q=0;q<16;++q) v[q]=0;
  {
    const int gc = (side ? cU : 0) + (base >> 15);       // global chunk
    const int w0 = (base & (HCB-1)) >> 1;                // first packed word (8 words = 16 bins)
    const u32* ps = part + (size_t)gc*HS*HWORDS + w0;
    for (int s=0; s<HS; ++s) {
      const uint4* pw = (const uint4*)(ps + (size_t)s*HWORDS);
      uint4 a = pw[0], b = pw[1];
      v[0]+= (int)(a.x&0xffffu); v[1]+= (int)(a.x>>16);
      v[2]+= (int)(a.y&0xffffu); v[3]+= (int)(a.y>>16);
      v[4]+= (int)(a.z&0xffffu); v[5]+= (int)(a.z>>16);
      v[6]+= (int)(a.w&0xffffu); v[7]+= (int)(a.w>>16);
      v[8]+= (int)(b.x&0xffffu); v[9]+= (int)(b.x>>16);
      v[10]+=(int)(b.y&0xffffu); v[11]+=(int)(b.y>>16);
      v[12]+=(int)(b.z&0xffffu); v[13]+=(int)(b.z>>16);
      v[14]+=(int)(b.w&0xffffu); v[15]+=(int)(b.w>>16);
    }
  }
  int sum = 0;
#pragma unroll
  for (int q=0;q<16;++q) sum += v[q];
  sa[tid] = sum; __syncthreads();
  int* src = sa; int* dst = sb;
  for (int off=1; off<256; off<<=1) {
    int x = src[tid] + ((tid>=off) ? src[tid-off] : 0);
    dst[tid] = x;
    __syncthreads();
    int* t = src; src = dst; dst = t;
  }
  const int incl = src[tid];
  int run = incl - sum;  // exclusive
#pragma unroll
  for (int q=0;q<16;++q){ int idx=base+q; if (idx<Nn) rp[idx]=run; run+=v[q]; }
  if (tid==255) bs[blockIdx.x] = incl;
}

__global__ void scan_blocks_kernel(int* bsU, int* bsI, int* rpU, int* rpI, int Nu, int Ni)
{
  if (threadIdx.x != 0) return;
  const int side = blockIdx.y;
  int* bs = side?bsI:bsU; int* rp = side?rpI:rpU;
  const int Nn = side?Ni:Nu;
  const int nb = (Nn+4095)>>12;
  int run = 0;
  for (int b=0;b<nb;++b){ int t=bs[b]; bs[b]=run; run+=t; }
  rp[Nn] = run;
}

__global__ __launch_bounds__(256) void scan_add_kernel(
    const int* bsU, const int* bsI, int* rpU, int* rpI, int Nu, int Ni)
{
  const int side = blockIdx.y;
  const int Nn = side?Ni:Nu;
  const int* bs = side?bsI:bsU;
  int* rp = side?rpI:rpU;
  const int nb = (Nn+4095)>>12;
  if ((int)blockIdx.x >= nb) return;
  const int add = bs[blockIdx.x];
  const int base = blockIdx.x*4096 + threadIdx.x*16;
#pragma unroll
  for (int q=0;q<16;++q){ int idx=base+q; if (idx<Nn) rp[idx]+=add; }
}

// scatter (r8/r9 form): both sides window on c. csrI keeps dest-windows;
// csrU gets per-row c-quartile grouping (r9: no spmm effect on a uniform
// random graph, but scatter itself was ~14us cheaper -- kept).
__global__ __launch_bounds__(256) void scatter_kernel(
    const int* __restrict__ rows, const int* __restrict__ cols, const float* __restrict__ vals,
    const int* __restrict__ rpU, const int* __restrict__ rpI,
    int* curU, int* curI, uint2* csrU, uint2* csrI, int E, int Nu, int Ni,
    int u0, int u1, int i0w, int i1w)
{
  (void)u0; (void)u1;
  int e = blockIdx.x*256 + threadIdx.x;
  if (e >= E) return;
  int r = rows[e], c = cols[e];
  if ((unsigned)r < (unsigned)Nu && (unsigned)c < (unsigned)Ni) {
    u32 vb = __float_as_uint(vals[e]);
    if (c >= i0w && c < i1w) {
      int su = rpU[r] + atomicAdd(&curU[r], 1);
      if ((unsigned)su < (unsigned)E) { uint2 t; t.x=(u32)c; t.y=vb; csrU[su]=t; }
      int si = rpI[c] + atomicAdd(&curI[c], 1);
      if ((unsigned)si < (unsigned)E) { uint2 t; t.x=(u32)r; t.y=vb; csrI[si]=t; }
    }
  }
}

// ---------- host ----------
extern "C" void kernel_launch(void* const* d_in, const int* in_sizes, int n_in,
                              void* d_out, int out_size, void* d_ws, size_t ws_size,
                              hipStream_t stream)
{
  const float* uE     = (const float*)d_in[0];
  const float* iE     = (const float*)d_in[1];
  const float* uhyper = (const float*)d_in[2];
  const float* ihyper = (const float*)d_in[3];
  const float* vals   = (const float*)d_in[4];
  const float* WhU    = (const float*)d_in[5];  // [L,3,128,128]
  const float* WhI    = (const float*)d_in[6];
  const float* WgU    = (const float*)d_in[7];  // [L,128,128]
  const float* WgI    = (const float*)d_in[8];
  const int*   rows   = (const int*)d_in[9];
  const int*   cols   = (const int*)d_in[10];
  const int U = in_sizes[0]/128;
  const int I = in_sizes[1]/128;
  const int E = in_sizes[4];
  const int L = in_sizes[7]/(128*128);
  (void)n_in; (void)out_size;

  float* Su = (float*)d_out;
  float* Si = Su + (size_t)U*128;

  char* base0 = (char*)d_ws;
  u16* uuH; u16* iiH; u16* PU; u16* PI; u16* YU; u16* TU; u16* pool3;
  uint2* csrU; uint2* csrI; int* rpU; int* rpI; int* cntU; int* cntI;
  int* bsU; int* bsI; float* Ru; float* Ri; float* latU; float* latI; float* Rp;
  {
    size_t off = 0;
    #define ALLOC(var, type, bytes) var = (type)(base0 + off); off = (off + (bytes) + 255) & ~(size_t)255;
    ALLOC(uuH,  u16*, (size_t)U*128*2)
    ALLOC(iiH,  u16*, (size_t)I*128*2)
    ALLOC(PU,   u16*, (size_t)U*128*2)
    ALLOC(PI,   u16*, (size_t)I*128*2)
    ALLOC(YU,   u16*, (size_t)U*128*2)      // Y_U (fp8, half used); reduce partials later
    ALLOC(TU,   u16*, (size_t)U*128*2)
    ALLOC(pool3,u16*, (size_t)I*128*2)      // Y_I (fp8) then T_I (bf16)
    ALLOC(csrU, uint2*, (size_t)E*8)
    ALLOC(csrI, uint2*, (size_t)E*8)
    ALLOC(rpU,  int*, (size_t)(U+1)*4)
    ALLOC(rpI,  int*, (size_t)(I+1)*4)
    ALLOC(cntU, int*, (size_t)U*4)
    ALLOC(cntI, int*, (size_t)I*4)
    ALLOC(bsU,  int*, 64*4)
    ALLOC(bsI,  int*, 64*4)
    ALLOC(Ru,   float*, 16384*4)
    ALLOC(Ri,   float*, 16384*4)
    ALLOC(latU, float*, 16384*4)
    ALLOC(latI, float*, 16384*4)
    ALLOC(Rp,   float*, (size_t)2*JS*16384*4)   // 2-stage reduce partials (2MB)
    #undef ALLOC
    if (off > ws_size) return;   // clean bail, graph-safe
  }
  const int cntN = (int)(((size_t)((char*)bsU - (char*)cntU)) / 4);

  const int nbU = (U+4095)>>12, nbI = (I+4095)>>12;
  const int nbMax = nbU > nbI ? nbU : nbI;
  const int rbU = (U+255)>>8, rbI = (I+255)>>8;   // reduce chunks (256 rows)
  const int gU = (U+63)/64, gI = (I+63)/64;        // MFMA gemm/update grids
  const int cU = (U + HCB-1)/HCB, cI = (I + HCB-1)/HCB;  // hist bin-chunks

  u32* hpart = (u32*)csrU;
  u8* Y8u = (u8*)YU;       // fp8 Y_U
  u8* Y8i = (u8*)pool3;    // fp8 Y_I

  // --- CSR build (both directions) ---
  hist_part_kernel<<<dim3(cU+cI, HS), 256, 0, stream>>>(rows, cols, hpart, E, cU);
  scan_local_kernel<<<dim3(nbMax,2), 256, 0, stream>>>(hpart,rpU,rpI,bsU,bsI,U,I,cU);
  scan_blocks_kernel<<<dim3(1,2), 64, 0, stream>>>(bsU,bsI,rpU,rpI,U,I);
  scan_add_kernel<<<dim3(nbMax,2), 256, 0, stream>>>(bsU,bsI,rpU,rpI,U,I);
  zero_kernel<<<(cntN+255)/256, 256, 0, stream>>>(cntU, cntN);
  for (int wnd = 0; wnd < 4; ++wnd) {
    int u0 = (int)(((long long)wnd   * U) / 4);
    int u1 = (int)(((long long)(wnd+1) * U) / 4);
    int i0w = (int)(((long long)wnd   * I) / 4);
    int i1w = (int)(((long long)(wnd+1) * I) / 4);
    scatter_kernel<<<(E+255)/256, 256, 0, stream>>>(
        rows, cols, vals, rpU, rpI, cntU, cntI, csrU, csrI, E, U, I,
        u0, u1, i0w, i1w);
  }

  // --- hyper embeddings (merged U+I, bf16 out) ---
  gemm128_dual<<<gU+gI, 256, 0, stream>>>(uE, (const u16*)0, uhyper, uuH, (u8*)0, U, gU,
                                          iE, (const u16*)0, ihyper, iiH, (u8*)0, I);

  for (int l=0; l<L; ++l) {
    const float* wgu = WgU + (size_t)l*16384;
    const float* wgi = WgI + (size_t)l*16384;
    const float* whu = WhU + (size_t)l*3*16384;
    const float* whi = WhI + (size_t)l*3*16384;
    const bool last = (l == L-1);
    if (l == 0) {
      // Y_I = iE@WgU -> Y8i(fp8) ; Y_U = uE@WgI -> Y8u(fp8)  (merged)
      gemm128_dual<<<gI+gU, 256, 0, stream>>>(iE, (const u16*)0, wgu, (u16*)0, Y8i, I, gI,
                                              uE, (const u16*)0, wgi, (u16*)0, Y8u, U);
      spmm_kernel<<<(U+3)/4, 256, 0, stream>>>(csrU, rpU, Y8i, TU, U, I, E);   // T_U
      spmm_kernel<<<(I+3)/4, 256, 0, stream>>>(csrI, rpI, Y8u, pool3, I, U, E); // T_I (pool3 reused)
      reduce_kernel<<<rbU+rbI, 256, 0, stream>>>(uuH,iiH, uE,(const u16*)0, iE,(const u16*)0, YU,U,I,rbU);
      reduce2a_kernel<<<dim3(64,JS,2), 256, 0, stream>>>(YU, Rp, rbU, rbI);
      reduce2b_kernel<<<dim3(64,2), 256, 0, stream>>>(Rp, Ru, Ri);
      fc_kernel<<<dim3(128,2), 128, 0, stream>>>(Ru,Ri,whu,whi,latU,latI);
      update_dual<<<gU+gI, 256, 0, stream>>>(
          TU,    uuH, latU, uE, (const u16*)0, PU, Su, U, gU,
          pool3, iiH, latI, iE, (const u16*)0, PI, Si, I, 1);
    } else {
      gemm128_dual<<<gI+gU, 256, 0, stream>>>((const float*)0, PI, wgu, (u16*)0, Y8i, I, gI,
                                              (const float*)0, PU, wgi, (u16*)0, Y8u, U);
      spmm_kernel<<<(U+3)/4, 256, 0, stream>>>(csrU, rpU, Y8i, TU, U, I, E);
      spmm_kernel<<<(I+3)/4, 256, 0, stream>>>(csrI, rpI, Y8u, pool3, I, U, E);
      reduce_kernel<<<rbU+rbI, 256, 0, stream>>>(uuH,iiH, (const float*)0,PU, (const float*)0,PI, YU,U,I,rbU);
      reduce2a_kernel<<<dim3(64,JS,2), 256, 0, stream>>>(YU, Rp, rbU, rbI);
      reduce2b_kernel<<<dim3(64,2), 256, 0, stream>>>(Rp, Ru, Ri);
      fc_kernel<<<dim3(128,2), 128, 0, stream>>>(Ru,Ri,whu,whi,latU,latI);
      update_dual<<<gU+gI, 256, 0, stream>>>(
          TU,    uuH, latU, (const float*)0, PU, last?(u16*)0:PU, Su, U, gU,
          pool3, iiH, latI, (const float*)0, PI, last?(u16*)0:PI, Si, I, 0);
    }
  }
}

// Round 11
// 891.814 us; speedup vs baseline: 1.0431x; 1.0431x over previous
//
#include <hip/hip_runtime.h>
#include <stdint.h>

#define LEAKY 0.1f
typedef unsigned short u16;
typedef unsigned int u32;
typedef unsigned char u8;
typedef short bf16x8 __attribute__((ext_vector_type(8)));
typedef float f32x4 __attribute__((ext_vector_type(4)));
typedef float f32x2 __attribute__((ext_vector_type(2)));

// ---------- bf16 helpers (storage = ushort) ----------
__device__ __forceinline__ float bflo(u32 u){ union{u32 i; float f;} c; c.i = u<<16; return c.f; }
__device__ __forceinline__ float bfhi(u32 u){ union{u32 i; float f;} c; c.i = u & 0xffff0000u; return c.f; }
__device__ __forceinline__ float bf2f(u16 v){ union{u32 i; float f;} c; c.i = ((u32)v)<<16; return c.f; }
__device__ __forceinline__ u16 f2bf(float f){
  union{float f; u32 i;} c; c.f = f;
  u32 r = (c.i + 0x7fffu + ((c.i>>16)&1u)) >> 16;
  return (u16)r;
}
__device__ __forceinline__ u32 pack2(float a, float b){ return (u32)f2bf(a) | ((u32)f2bf(b)<<16); }

// ---------- fp8 e4m3fn helpers ----------
// encode (soft, OCP e4m3 bias-7, RNE, clamp 448, never emits 0x7F/NaN)
__device__ __forceinline__ u32 f2fp8(float f){
  union{float f; u32 i;} c; c.f = f;
  u32 s = (c.i >> 24) & 0x80u;
  float a = fabsf(f); if (a > 448.f) a = 448.f;
  union{float f; u32 i;} d; d.f = a * 0x1p-120f;
  u32 u = d.i;
  u32 r = (u + 0x7FFFFu + ((u >> 20) & 1u)) >> 20;
  if (r > 0x7Eu) r = 0x7Eu;
  return s | r;
}
// decode: gfx950 HW packed convert (OCP e4m3fn) -- r10 soft decode cost 8
// VALU/edge and flipped spmm to VALU-bound (68% busy); this is 1 op.
__device__ __forceinline__ f32x2 fp8x2_to_f(u32 b2){
  return __builtin_amdgcn_cvt_pk_f32_fp8((int)b2, false);
}

__device__ __forceinline__ void load8f(const float* p, float* v){
  const float4* q = (const float4*)p; float4 a = q[0], b = q[1];
  v[0]=a.x;v[1]=a.y;v[2]=a.z;v[3]=a.w;v[4]=b.x;v[5]=b.y;v[6]=b.z;v[7]=b.w;
}
__device__ __forceinline__ void load8h(const u16* p, float* v){
  uint4 u = *(const uint4*)p;
  v[0]=bflo(u.x);v[1]=bfhi(u.x);v[2]=bflo(u.y);v[3]=bfhi(u.y);
  v[4]=bflo(u.z);v[5]=bfhi(u.z);v[6]=bflo(u.w);v[7]=bfhi(u.w);
}
__device__ __forceinline__ void load4f(const float* p, float* v){
  float4 a = *(const float4*)p; v[0]=a.x;v[1]=a.y;v[2]=a.z;v[3]=a.w;
}
__device__ __forceinline__ void load4h(const u16* p, float* v){
  uint2 u = *(const uint2*)p;
  v[0]=bflo(u.x); v[1]=bfhi(u.x); v[2]=bflo(u.y); v[3]=bfhi(u.y);
}
__device__ __forceinline__ void store2bf(u16* p, float a, float b){
  *(u32*)p = pack2(a,b);
}
__device__ __forceinline__ void store4bf(u16* p, float a, float b, float c, float d){
  uint2 t; t.x = pack2(a,b); t.y = pack2(c,d);
  *(uint2*)p = t;
}

// ---------- misc: zero an int buffer ----------
__global__ __launch_bounds__(256) void zero_kernel(int* p, int n){
  int i = blockIdx.x*256 + threadIdx.x;
  if (i < n) p[i] = 0;
}

// ---------- stage W[128][128] fp32 -> LDS transposed bf16 Wt[n][k], stride 136 ----------
__device__ __forceinline__ void stageWt(const float* __restrict__ W, u16* Wt, int tid){
  const int n = tid & 127, khalf = tid >> 7;
#pragma unroll
  for (int g = 0; g < 16; ++g) {
    int k0 = khalf*64 + g*4;
    float w0 = W[(k0+0)*128 + n];
    float w1 = W[(k0+1)*128 + n];
    float w2 = W[(k0+2)*128 + n];
    float w3 = W[(k0+3)*128 + n];
    uint2 t; t.x = pack2(w0,w1); t.y = pack2(w2,w3);
    *(uint2*)&Wt[n*136 + k0] = t;
  }
}

// ---------- MFMA GEMM core: C[N,128] = A[N,128] @ W[128,128] ----------
// Output: bf16 (C) or fp8 e4m3 (C8, when non-null -- Y gather payload).
__device__ __forceinline__ void gemm_core(
    const float* __restrict__ Af, const u16* __restrict__ Ah,
    const float* __restrict__ W, u16* __restrict__ C, u8* __restrict__ C8,
    int N, int brow, u16* Wt, int tid)
{
  stageWt(W, Wt, tid);
  __syncthreads();

  const int w = tid >> 6, lane = tid & 63;
  const int m = lane & 15, quad = lane >> 4;
  const int rowBase = brow*64 + w*16;
  int arow = rowBase + m;
  if (arow >= N) arow = N-1;

  bf16x8 af[4];
  if (Ah) {
#pragma unroll
    for (int kt=0; kt<4; ++kt)
      af[kt] = *(const bf16x8*)(Ah + (size_t)arow*128 + kt*32 + quad*8);
  } else {
#pragma unroll
    for (int kt=0; kt<4; ++kt) {
      float v[8]; load8f(Af + (size_t)arow*128 + kt*32 + quad*8, v);
      bf16x8 t;
#pragma unroll
      for (int j=0;j<8;++j) t[j] = (short)f2bf(v[j]);
      af[kt] = t;
    }
  }

#pragma unroll
  for (int jt=0; jt<8; ++jt) {
    f32x4 acc = {0.f,0.f,0.f,0.f};
#pragma unroll
    for (int kt=0; kt<4; ++kt) {
      bf16x8 bf = *(const bf16x8*)&Wt[(jt*16+m)*136 + kt*32 + quad*8];
      acc = __builtin_amdgcn_mfma_f32_16x16x32_bf16(af[kt], bf, acc, 0, 0, 0);
    }
    const int col = jt*16 + m;
#pragma unroll
    for (int r=0;r<4;++r) {
      int rg = rowBase + quad*4 + r;
      if (rg < N) {
        if (C8) C8[(size_t)rg*128 + col] = (u8)f2fp8(acc[r]);
        else    C[(size_t)rg*128 + col] = f2bf(acc[r]);
      }
    }
  }
}

// dual GEMM: blocks [0,g1) -> side1, rest -> side2
__global__ __launch_bounds__(256) void gemm128_dual(
    const float* Af1, const u16* Ah1, const float* W1, u16* C1, u8* C81, int N1, int g1,
    const float* Af2, const u16* Ah2, const float* W2, u16* C2, u8* C82, int N2)
{
  __shared__ alignas(16) u16 Wt[128*136];
  const int b = blockIdx.x;
  if (b < g1) gemm_core(Af1, Ah1, W1, C1, C81, N1, b,      Wt, threadIdx.x);
  else        gemm_core(Af2, Ah2, W2, C2, C82, N2, b - g1, Wt, threadIdx.x);
}

// dual update kernel
__global__ __launch_bounds__(256) void update_dual(
    const u16* T1, const u16* Hy1, const float* W1,
    const float* PF1, const u16* PH1, u16* Po1, float* S1, int N1, int g1,
    const u16* T2, const u16* Hy2, const float* W2,
    const float* PF2, const u16* PH2, u16* Po2, float* S2, int N2, int initS)
{
  __shared__ alignas(16) char shmem[34816];  // union: Wt u16[128*136] | Gs f32[64*132]
  u16* Wt = (u16*)shmem;
  float* Gs = (float*)shmem;
  const int tid = threadIdx.x;
  const int b = blockIdx.x;

  const u16* T; const u16* Hy; const float* latW;
  const float* PrevF; const u16* PrevH; u16* Pout; float* S; int N; int brow;
  if (b < g1) { T=T1; Hy=Hy1; latW=W1; PrevF=PF1; PrevH=PH1; Pout=Po1; S=S1; N=N1; brow=b; }
  else        { T=T2; Hy=Hy2; latW=W2; PrevF=PF2; PrevH=PH2; Pout=Po2; S=S2; N=N2; brow=b-g1; }

  stageWt(latW, Wt, tid);
  __syncthreads();

  const int w = tid >> 6, lane = tid & 63;
  const int m = lane & 15, quad = lane >> 4;
  const int rowBase = brow*64;
  int arow = rowBase + w*16 + m;
  if (arow >= N) arow = N-1;

  bf16x8 af[4];
#pragma unroll
  for (int kt=0; kt<4; ++kt)
    af[kt] = *(const bf16x8*)(Hy + (size_t)arow*128 + kt*32 + quad*8);

  f32x4 acc[8];
#pragma unroll
  for (int jt=0; jt<8; ++jt) {
    f32x4 a = {0.f,0.f,0.f,0.f};
#pragma unroll
    for (int kt=0; kt<4; ++kt) {
      bf16x8 bf = *(const bf16x8*)&Wt[(jt*16+m)*136 + kt*32 + quad*8];
      a = __builtin_amdgcn_mfma_f32_16x16x32_bf16(af[kt], bf, a, 0, 0, 0);
    }
    acc[jt] = a;
  }
  __syncthreads();   // all Wt reads done; reuse LDS as Gs
#pragma unroll
  for (int jt=0; jt<8; ++jt) {
#pragma unroll
    for (int r=0;r<4;++r) {
      float x = acc[jt][r];
      Gs[(w*16 + quad*4 + r)*132 + jt*16 + m] = x > 0.f ? x : LEAKY*x;
    }
  }
  __syncthreads();

  const int c4 = (tid & 31) * 4;
  const int r0 = tid >> 5;
#pragma unroll
  for (int ri=0; ri<8; ++ri) {
    int lr = r0 + ri*8;           // 0..63
    int n = rowBase + lr;
    if (n >= N) continue;
    size_t off = (size_t)n*128 + c4;
    float gv[4]; load4f(&Gs[lr*132 + c4], gv);
    float tv[4], pv[4], ov[4];
    load4h(T + off, tv);
    if (PrevH) load4h(PrevH + off, pv);
    else       load4f(PrevF + off, pv);
#pragma unroll
    for (int cc=0;cc<4;++cc) ov[cc] = gv[cc] + tv[cc] + pv[cc];
    if (Pout)
      store4bf(&Pout[off], ov[0],ov[1],ov[2],ov[3]);
    if (initS) {
      float4 s; s.x=pv[0]+ov[0]; s.y=pv[1]+ov[1]; s.z=pv[2]+ov[2]; s.w=pv[3]+ov[3];
      *(float4*)&S[off] = s;
    } else {
      float4 s = *(const float4*)&S[off];
      s.x += ov[0]; s.y += ov[1]; s.z += ov[2]; s.w += ov[3];
      *(float4*)&S[off] = s;
    }
  }
}

// ---------- hyper reduce v2 (MFMA): part[b] = Hy_chunk^T @ Lat_chunk ----------
#define RPAD 40
__global__ __launch_bounds__(256) void reduce_kernel(
    const u16* __restrict__ HyU, const u16* __restrict__ HyI,
    const float* __restrict__ LatUf, const u16* __restrict__ LatUh,
    const float* __restrict__ LatIf, const u16* __restrict__ LatIh,
    u16* __restrict__ part, int Nu, int Ni, int nbU)
{
  __shared__ alignas(16) u16 HsT[128*RPAD];
  __shared__ alignas(16) u16 LsT[128*RPAD];
  const int b = blockIdx.x;
  const u16* Hy; const float* Lf; const u16* Lh; int N, cstart;
  if (b < nbU) { Hy=HyU; Lf=LatUf; Lh=LatUh; N=Nu; cstart = b*256; }
  else         { Hy=HyI; Lf=LatIf; Lh=LatIh; N=Ni; cstart = (b-nbU)*256; }
  const int cend = (N < cstart+256) ? N : (cstart+256);
  const int tid = threadIdx.x;
  const int w = tid >> 6, lane = tid & 63;
  const int m = lane & 15, quad = lane >> 4;

  f32x4 acc[2][8];
#pragma unroll
  for (int a=0;a<2;++a)
#pragma unroll
    for (int c=0;c<8;++c) { acc[a][c][0]=0.f; acc[a][c][1]=0.f; acc[a][c][2]=0.f; acc[a][c][3]=0.f; }

  for (int t0 = cstart; t0 < cend; t0 += 32) {
#pragma unroll
    for (int it=0; it<2; ++it) {
      const int idx = it*256 + tid;
      const int n = idx & 31, h0 = (idx >> 5) * 8;
      const int row = t0 + n;
      u32 ax=0, ay=0, az=0, aw=0, lx=0, ly=0, lz=0, lw=0;
      if (row < cend) {
        uint4 uh = *(const uint4*)(Hy + (size_t)row*128 + h0);
        ax=uh.x; ay=uh.y; az=uh.z; aw=uh.w;
        if (Lh) {
          uint4 ul = *(const uint4*)(Lh + (size_t)row*128 + h0);
          lx=ul.x; ly=ul.y; lz=ul.z; lw=ul.w;
        } else {
          float v[8]; load8f(Lf + (size_t)row*128 + h0, v);
          lx = pack2(v[0],v[1]); ly = pack2(v[2],v[3]);
          lz = pack2(v[4],v[5]); lw = pack2(v[6],v[7]);
        }
      }
      u16* hp = &HsT[h0*RPAD + n];
      hp[0*RPAD]=(u16)ax; hp[1*RPAD]=(u16)(ax>>16);
      hp[2*RPAD]=(u16)ay; hp[3*RPAD]=(u16)(ay>>16);
      hp[4*RPAD]=(u16)az; hp[5*RPAD]=(u16)(az>>16);
      hp[6*RPAD]=(u16)aw; hp[7*RPAD]=(u16)(aw>>16);
      u16* lp = &LsT[h0*RPAD + n];
      lp[0*RPAD]=(u16)lx; lp[1*RPAD]=(u16)(lx>>16);
      lp[2*RPAD]=(u16)ly; lp[3*RPAD]=(u16)(ly>>16);
      lp[4*RPAD]=(u16)lz; lp[5*RPAD]=(u16)(lz>>16);
      lp[6*RPAD]=(u16)lw; lp[7*RPAD]=(u16)(lw>>16);
    }
    __syncthreads();
    bf16x8 a0 = *(const bf16x8*)&HsT[(w*32 +      m)*RPAD + quad*8];
    bf16x8 a1 = *(const bf16x8*)&HsT[(w*32 + 16 + m)*RPAD + quad*8];
#pragma unroll
    for (int td=0; td<8; ++td) {
      bf16x8 bfr = *(const bf16x8*)&LsT[(td*16 + m)*RPAD + quad*8];
      acc[0][td] = __builtin_amdgcn_mfma_f32_16x16x32_bf16(a0, bfr, acc[0][td], 0, 0, 0);
      acc[1][td] = __builtin_amdgcn_mfma_f32_16x16x32_bf16(a1, bfr, acc[1][td], 0, 0, 0);
    }
    __syncthreads();
  }
  u16* pb = part + (size_t)b*16384;
#pragma unroll
  for (int th=0; th<2; ++th) {
    const int h = w*32 + th*16 + quad*4;
#pragma unroll
    for (int td=0; td<8; ++td) {
      const int d = td*16 + m;
#pragma unroll
      for (int r=0;r<4;++r)
        pb[(size_t)(h+r)*128 + d] = f2bf(acc[th][td][r]);
    }
  }
}

// ---------- 2-stage partial reduction ----------
#define JS 16
__global__ __launch_bounds__(256) void reduce2a_kernel(
    const u16* __restrict__ part, float* __restrict__ Rp,
    int nbU, int nbI)
{
  const int e = blockIdx.x*256 + threadIdx.x;   // 0..16383
  const int side = blockIdx.z;
  const int nb = side ? nbI : nbU;
  const int per = (nb + JS - 1) / JS;
  const int j0 = blockIdx.y * per;
  int j1 = j0 + per; if (j1 > nb) j1 = nb;
  const u16* p = part + (side ? (size_t)nbU*16384 : 0) + e;
  float s = 0.f;
  for (int j=j0; j<j1; ++j) s += bf2f(p[(size_t)j*16384]);
  Rp[((size_t)side*JS + blockIdx.y)*16384 + e] = s;
}

__global__ __launch_bounds__(256) void reduce2b_kernel(
    const float* __restrict__ Rp, float* __restrict__ Ru, float* __restrict__ Ri)
{
  const int e = blockIdx.x*256 + threadIdx.x;   // 0..16383
  const int side = blockIdx.y;
  const float* p = Rp + (size_t)side*JS*16384 + e;
  float s = 0.f;
#pragma unroll
  for (int j=0; j<JS; ++j) s += p[(size_t)j*16384];
  if (side) Ri[e] = s; else Ru[e] = s;
}

// ---------- FC chain ----------
__global__ __launch_bounds__(128) void fc_kernel(
    const float* __restrict__ Ru, const float* __restrict__ Ri,
    const float* __restrict__ W3u, const float* __restrict__ W3i,
    float* __restrict__ latU, float* __restrict__ latI)
{
  __shared__ float cur[128];
  const int h = threadIdx.x;
  const int d = blockIdx.x;
  const int side = blockIdx.y;
  const float* R  = side ? Ri  : Ru;
  const float* W3 = side ? W3i : W3u;
  float* lat      = side ? latI : latU;
  float x = R[h*128 + d];
  cur[h] = x > 0.f ? x : LEAKY*x;
  __syncthreads();
  for (int s=0;s<3;++s) {
    const float* w = W3 + s*16384 + h;
    float val = 0.f;
#pragma unroll 8
    for (int hp=0; hp<128; ++hp) val = fmaf(cur[hp], w[hp*128], val);
    val = (val > 0.f ? val : 0.f) + cur[h];
    __syncthreads();
    cur[h] = val;
    __syncthreads();
  }
  lat[h*128+d] = cur[h];
}

// ---------- CSR-based SpMM: T[row,:] = relu( sum_e val_e * Y[idx_e,:] ) ----------
// r9: fp8 payload halved FETCH (154->63MB) but soft decode tripled VALU
// (38->68%) and cost +7us. r10: HW v_cvt_pk_f32_fp8 (OCP e4m3fn on gfx950)
// decodes the lane's 2 bytes in ONE VALU op.
__global__ __launch_bounds__(256) void spmm_kernel(
    const uint2* __restrict__ csr, const int* __restrict__ rowptr,
    const u8* __restrict__ Y, u16* __restrict__ T, int N, int Ncol, int E)
{
  const int lane = threadIdx.x & 63;
  const int row = blockIdx.x*4 + (threadIdx.x >> 6);
  if (row >= N) return;
  int e  = rowptr[row];
  int e1 = rowptr[row+1];
  if (e < 0) e = 0;
  if (e > E) e = E;
  if (e1 < e) e1 = e;
  if (e1 > E) e1 = E;
  const u32 cmax = (u32)(Ncol - 1);
  float a0=0.f, a1=0.f;
  const int c2 = lane*2;
  for (; e+4 <= e1; e += 4) {
    uint2 p0 = csr[e], p1 = csr[e+1], p2 = csr[e+2], p3 = csr[e+3];
    u32 i0 = p0.x < cmax ? p0.x : cmax;
    u32 i1 = p1.x < cmax ? p1.x : cmax;
    u32 i2 = p2.x < cmax ? p2.x : cmax;
    u32 i3 = p3.x < cmax ? p3.x : cmax;
    u32 y0 = *(const u16*)&Y[(size_t)i0*128 + c2];
    u32 y1 = *(const u16*)&Y[(size_t)i1*128 + c2];
    u32 y2 = *(const u16*)&Y[(size_t)i2*128 + c2];
    u32 y3 = *(const u16*)&Y[(size_t)i3*128 + c2];
    float v0 = __uint_as_float(p0.y), v1 = __uint_as_float(p1.y);
    float v2 = __uint_as_float(p2.y), v3 = __uint_as_float(p3.y);
    f32x2 d0 = fp8x2_to_f(y0), d1 = fp8x2_to_f(y1);
    f32x2 d2 = fp8x2_to_f(y2), d3 = fp8x2_to_f(y3);
    a0 = fmaf(v0, d0[0], a0); a1 = fmaf(v0, d0[1], a1);
    a0 = fmaf(v1, d1[0], a0); a1 = fmaf(v1, d1[1], a1);
    a0 = fmaf(v2, d2[0], a0); a1 = fmaf(v2, d2[1], a1);
    a0 = fmaf(v3, d3[0], a0); a1 = fmaf(v3, d3[1], a1);
  }
  for (; e < e1; ++e) {
    uint2 p0 = csr[e];
    u32 i0 = p0.x < cmax ? p0.x : cmax;
    u32 y0 = *(const u16*)&Y[(size_t)i0*128 + c2];
    float v0 = __uint_as_float(p0.y);
    f32x2 d0 = fp8x2_to_f(y0);
    a0 = fmaf(v0, d0[0], a0); a1 = fmaf(v0, d0[1], a1);
  }
  store2bf(&T[(size_t)row*128 + c2], a0 > 0.f ? a0 : 0.f, a1 > 0.f ? a1 : 0.f);
}

// ---------- CSR build ----------
#define HCB 32768              // bins per chunk (u16-packed)
#define HWORDS (HCB/2)         // 16384 u32 words = 64KB
#define HS  64                 // edge slices
__global__ __launch_bounds__(256) void hist_part_kernel(
    const int* __restrict__ rows, const int* __restrict__ cols,
    u32* __restrict__ part, int E, int cU)
{
  __shared__ alignas(16) u32 h[HWORDS];
  const int c = blockIdx.x, s = blockIdx.y;
  const int* key = (c < cU) ? rows : cols;
  const u32 lo = (u32)((c < cU ? c : c - cU) * HCB);
  {
    uint4 z; z.x=0; z.y=0; z.z=0; z.w=0;
    uint4* h4 = (uint4*)h;
    for (int i = threadIdx.x; i < HWORDS/4; i += 256) h4[i] = z;
  }
  __syncthreads();
  int per = (E + HS - 1) / HS;
  per = (per + 3) & ~3;                      // multiple of 4: int4-aligned slices
  const int e0 = s*per;
  const int e1 = (E < e0+per) ? E : (e0+per);
  if (e0 < e1) {
    const int4* kp = (const int4*)(key + e0);
    const int nv = (e1 - e0) >> 2;
    for (int i = threadIdx.x; i < nv; i += 256) {
      int4 kv = kp[i];
      u32 k0=(u32)kv.x-lo, k1=(u32)kv.y-lo, k2=(u32)kv.z-lo, k3=(u32)kv.w-lo;
      if (k0 < (u32)HCB) atomicAdd(&h[k0>>1], 1u << ((k0&1)<<4));
      if (k1 < (u32)HCB) atomicAdd(&h[k1>>1], 1u << ((k1&1)<<4));
      if (k2 < (u32)HCB) atomicAdd(&h[k2>>1], 1u << ((k2&1)<<4));
      if (k3 < (u32)HCB) atomicAdd(&h[k3>>1], 1u << ((k3&1)<<4));
    }
    for (int e = e0 + (nv<<2) + threadIdx.x; e < e1; e += 256) {
      u32 k = (u32)key[e] - lo;
      if (k < (u32)HCB) atomicAdd(&h[k>>1], 1u << ((k&1)<<4));
    }
  }
  __syncthreads();
  uint4* dst = (uint4*)(part + (size_t)(c*HS + s) * HWORDS);
  const uint4* h4 = (const uint4*)h;
  for (int i = threadIdx.x; i < HWORDS/4; i += 256) dst[i] = h4[i];
}

__global__ __launch_bounds__(256) void scan_local_kernel(
    const u32* __restrict__ part,
    int* rpU, int* rpI, int* bsU, int* bsI, int Nu, int Ni, int cU)
{
  const int side = blockIdx.y;
  const int Nn = side ? Ni : Nu;
  int* rp = side ? rpI : rpU;
  int* bs = side ? bsI : bsU;
  const int nb = (Nn + 4095) >> 12;
  if ((int)blockIdx.x >= nb) return;
  __shared__ int sa[256], sb[256];
  const int tid = threadIdx.x;
  const int base = blockIdx.x*4096 + tid*16;   // 16 bins; never crosses a 32768 chunk boundary
  int v[16];
#pragma unroll
  for (int q=0;q<16;++q) v[q]=0;
  {
    const int gc = (side ? cU : 0) + (base >> 15);       // global chunk
    const int w0 = (base & (HCB-1)) >> 1;                // first packed word (8 words = 16 bins)
    const u32* ps = part + (size_t)gc*HS*HWORDS + w0;
    for (int s=0; s<HS; ++s) {
      const uint4* pw = (const uint4*)(ps + (size_t)s*HWORDS);
      uint4 a = pw[0], b = pw[1];
      v[0]+= (int)(a.x&0xffffu); v[1]+= (int)(a.x>>16);
      v[2]+= (int)(a.y&0xffffu); v[3]+= (int)(a.y>>16);
      v[4]+= (int)(a.z&0xffffu); v[5]+= (int)(a.z>>16);
      v[6]+= (int)(a.w&0xffffu); v[7]+= (int)(a.w>>16);
      v[8]+= (int)(b.x&0xffffu); v[9]+= (int)(b.x>>16);
      v[10]+=(int)(b.y&0xffffu); v[11]+=(int)(b.y>>16);
      v[12]+=(int)(b.z&0xffffu); v[13]+=(int)(b.z>>16);
      v[14]+=(int)(b.w&0xffffu); v[15]+=(int)(b.w>>16);
    }
  }
  int sum = 0;
#pragma unroll
  for (int q=0;q<16;++q) sum += v[q];
  sa[tid] = sum; __syncthreads();
  int* src = sa; int* dst = sb;
  for (int off=1; off<256; off<<=1) {
    int x = src[tid] + ((tid>=off) ? src[tid-off] : 0);
    dst[tid] = x;
    __syncthreads();
    int* t = src; src = dst; dst = t;
  }
  const int incl = src[tid];
  int run = incl - sum;  // exclusive
#pragma unroll
  for (int q=0;q<16;++q){ int idx=base+q; if (idx<Nn) rp[idx]=run; run+=v[q]; }
  if (tid==255) bs[blockIdx.x] = incl;
}

__global__ void scan_blocks_kernel(int* bsU, int* bsI, int* rpU, int* rpI, int Nu, int Ni)
{
  if (threadIdx.x != 0) return;
  const int side = blockIdx.y;
  int* bs = side?bsI:bsU; int* rp = side?rpI:rpU;
  const int Nn = side?Ni:Nu;
  const int nb = (Nn+4095)>>12;
  int run = 0;
  for (int b=0;b<nb;++b){ int t=bs[b]; bs[b]=run; run+=t; }
  rp[Nn] = run;
}

__global__ __launch_bounds__(256) void scan_add_kernel(
    const int* bsU, const int* bsI, int* rpU, int* rpI, int Nu, int Ni)
{
  const int side = blockIdx.y;
  const int Nn = side?Ni:Nu;
  const int* bs = side?bsI:bsU;
  int* rp = side?rpI:rpU;
  const int nb = (Nn+4095)>>12;
  if ((int)blockIdx.x >= nb) return;
  const int add = bs[blockIdx.x];
  const int base = blockIdx.x*4096 + threadIdx.x*16;
#pragma unroll
  for (int q=0;q<16;++q){ int idx=base+q; if (idx<Nn) rp[idx]+=add; }
}

// scatter (r8/r9 form): both sides window on c.
__global__ __launch_bounds__(256) void scatter_kernel(
    const int* __restrict__ rows, const int* __restrict__ cols, const float* __restrict__ vals,
    const int* __restrict__ rpU, const int* __restrict__ rpI,
    int* curU, int* curI, uint2* csrU, uint2* csrI, int E, int Nu, int Ni,
    int u0, int u1, int i0w, int i1w)
{
  (void)u0; (void)u1;
  int e = blockIdx.x*256 + threadIdx.x;
  if (e >= E) return;
  int r = rows[e], c = cols[e];
  if ((unsigned)r < (unsigned)Nu && (unsigned)c < (unsigned)Ni) {
    u32 vb = __float_as_uint(vals[e]);
    if (c >= i0w && c < i1w) {
      int su = rpU[r] + atomicAdd(&curU[r], 1);
      if ((unsigned)su < (unsigned)E) { uint2 t; t.x=(u32)c; t.y=vb; csrU[su]=t; }
      int si = rpI[c] + atomicAdd(&curI[c], 1);
      if ((unsigned)si < (unsigned)E) { uint2 t; t.x=(u32)r; t.y=vb; csrI[si]=t; }
    }
  }
}

// ---------- host ----------
extern "C" void kernel_launch(void* const* d_in, const int* in_sizes, int n_in,
                              void* d_out, int out_size, void* d_ws, size_t ws_size,
                              hipStream_t stream)
{
  const float* uE     = (const float*)d_in[0];
  const float* iE     = (const float*)d_in[1];
  const float* uhyper = (const float*)d_in[2];
  const float* ihyper = (const float*)d_in[3];
  const float* vals   = (const float*)d_in[4];
  const float* WhU    = (const float*)d_in[5];  // [L,3,128,128]
  const float* WhI    = (const float*)d_in[6];
  const float* WgU    = (const float*)d_in[7];  // [L,128,128]
  const float* WgI    = (const float*)d_in[8];
  const int*   rows   = (const int*)d_in[9];
  const int*   cols   = (const int*)d_in[10];
  const int U = in_sizes[0]/128;
  const int I = in_sizes[1]/128;
  const int E = in_sizes[4];
  const int L = in_sizes[7]/(128*128);
  (void)n_in; (void)out_size;

  float* Su = (float*)d_out;
  float* Si = Su + (size_t)U*128;

  char* base0 = (char*)d_ws;
  u16* uuH; u16* iiH; u16* PU; u16* PI; u16* YU; u16* TU; u16* pool3;
  uint2* csrU; uint2* csrI; int* rpU; int* rpI; int* cntU; int* cntI;
  int* bsU; int* bsI; float* Ru; float* Ri; float* latU; float* latI; float* Rp;
  {
    size_t off = 0;
    #define ALLOC(var, type, bytes) var = (type)(base0 + off); off = (off + (bytes) + 255) & ~(size_t)255;
    ALLOC(uuH,  u16*, (size_t)U*128*2)
    ALLOC(iiH,  u16*, (size_t)I*128*2)
    ALLOC(PU,   u16*, (size_t)U*128*2)
    ALLOC(PI,   u16*, (size_t)I*128*2)
    ALLOC(YU,   u16*, (size_t)U*128*2)      // Y_U (fp8, half used); reduce partials later
    ALLOC(TU,   u16*, (size_t)U*128*2)
    ALLOC(pool3,u16*, (size_t)I*128*2)      // Y_I (fp8) then T_I (bf16)
    ALLOC(csrU, uint2*, (size_t)E*8)
    ALLOC(csrI, uint2*, (size_t)E*8)
    ALLOC(rpU,  int*, (size_t)(U+1)*4)
    ALLOC(rpI,  int*, (size_t)(I+1)*4)
    ALLOC(cntU, int*, (size_t)U*4)
    ALLOC(cntI, int*, (size_t)I*4)
    ALLOC(bsU,  int*, 64*4)
    ALLOC(bsI,  int*, 64*4)
    ALLOC(Ru,   float*, 16384*4)
    ALLOC(Ri,   float*, 16384*4)
    ALLOC(latU, float*, 16384*4)
    ALLOC(latI, float*, 16384*4)
    ALLOC(Rp,   float*, (size_t)2*JS*16384*4)   // 2-stage reduce partials (2MB)
    #undef ALLOC
    if (off > ws_size) return;   // clean bail, graph-safe
  }
  const int cntN = (int)(((size_t)((char*)bsU - (char*)cntU)) / 4);

  const int nbU = (U+4095)>>12, nbI = (I+4095)>>12;
  const int nbMax = nbU > nbI ? nbU : nbI;
  const int rbU = (U+255)>>8, rbI = (I+255)>>8;   // reduce chunks (256 rows)
  const int gU = (U+63)/64, gI = (I+63)/64;        // MFMA gemm/update grids
  const int cU = (U + HCB-1)/HCB, cI = (I + HCB-1)/HCB;  // hist bin-chunks

  u32* hpart = (u32*)csrU;
  u8* Y8u = (u8*)YU;       // fp8 Y_U
  u8* Y8i = (u8*)pool3;    // fp8 Y_I

  // --- CSR build (both directions) ---
  hist_part_kernel<<<dim3(cU+cI, HS), 256, 0, stream>>>(rows, cols, hpart, E, cU);
  scan_local_kernel<<<dim3(nbMax,2), 256, 0, stream>>>(hpart,rpU,rpI,bsU,bsI,U,I,cU);
  scan_blocks_kernel<<<dim3(1,2), 64, 0, stream>>>(bsU,bsI,rpU,rpI,U,I);
  scan_add_kernel<<<dim3(nbMax,2), 256, 0, stream>>>(bsU,bsI,rpU,rpI,U,I);
  zero_kernel<<<(cntN+255)/256, 256, 0, stream>>>(cntU, cntN);
  for (int wnd = 0; wnd < 4; ++wnd) {
    int u0 = (int)(((long long)wnd   * U) / 4);
    int u1 = (int)(((long long)(wnd+1) * U) / 4);
    int i0w = (int)(((long long)wnd   * I) / 4);
    int i1w = (int)(((long long)(wnd+1) * I) / 4);
    scatter_kernel<<<(E+255)/256, 256, 0, stream>>>(
        rows, cols, vals, rpU, rpI, cntU, cntI, csrU, csrI, E, U, I,
        u0, u1, i0w, i1w);
  }

  // --- hyper embeddings (merged U+I, bf16 out) ---
  gemm128_dual<<<gU+gI, 256, 0, stream>>>(uE, (const u16*)0, uhyper, uuH, (u8*)0, U, gU,
                                          iE, (const u16*)0, ihyper, iiH, (u8*)0, I);

  for (int l=0; l<L; ++l) {
    const float* wgu = WgU + (size_t)l*16384;
    const float* wgi = WgI + (size_t)l*16384;
    const float* whu = WhU + (size_t)l*3*16384;
    const float* whi = WhI + (size_t)l*3*16384;
    const bool last = (l == L-1);
    if (l == 0) {
      // Y_I = iE@WgU -> Y8i(fp8) ; Y_U = uE@WgI -> Y8u(fp8)  (merged)
      gemm128_dual<<<gI+gU, 256, 0, stream>>>(iE, (const u16*)0, wgu, (u16*)0, Y8i, I, gI,
                                              uE, (const u16*)0, wgi, (u16*)0, Y8u, U);
      spmm_kernel<<<(U+3)/4, 256, 0, stream>>>(csrU, rpU, Y8i, TU, U, I, E);   // T_U
      spmm_kernel<<<(I+3)/4, 256, 0, stream>>>(csrI, rpI, Y8u, pool3, I, U, E); // T_I (pool3 reused)
      reduce_kernel<<<rbU+rbI, 256, 0, stream>>>(uuH,iiH, uE,(const u16*)0, iE,(const u16*)0, YU,U,I,rbU);
      reduce2a_kernel<<<dim3(64,JS,2), 256, 0, stream>>>(YU, Rp, rbU, rbI);
      reduce2b_kernel<<<dim3(64,2), 256, 0, stream>>>(Rp, Ru, Ri);
      fc_kernel<<<dim3(128,2), 128, 0, stream>>>(Ru,Ri,whu,whi,latU,latI);
      update_dual<<<gU+gI, 256, 0, stream>>>(
          TU,    uuH, latU, uE, (const u16*)0, PU, Su, U, gU,
          pool3, iiH, latI, iE, (const u16*)0, PI, Si, I, 1);
    } else {
      gemm128_dual<<<gI+gU, 256, 0, stream>>>((const float*)0, PI, wgu, (u16*)0, Y8i, I, gI,
                                              (const float*)0, PU, wgi, (u16*)0, Y8u, U);
      spmm_kernel<<<(U+3)/4, 256, 0, stream>>>(csrU, rpU, Y8i, TU, U, I, E);
      spmm_kernel<<<(I+3)/4, 256, 0, stream>>>(csrI, rpI, Y8u, pool3, I, U, E);
      reduce_kernel<<<rbU+rbI, 256, 0, stream>>>(uuH,iiH, (const float*)0,PU, (const float*)0,PI, YU,U,I,rbU);
      reduce2a_kernel<<<dim3(64,JS,2), 256, 0, stream>>>(YU, Rp, rbU, rbI);
      reduce2b_kernel<<<dim3(64,2), 256, 0, stream>>>(Rp, Ru, Ri);
      fc_kernel<<<dim3(128,2), 128, 0, stream>>>(Ru,Ri,whu,whi,latU,latI);
      update_dual<<<gU+gI, 256, 0, stream>>>(
          TU,    uuH, latU, (const float*)0, PU, last?(u16*)0:PU, Su, U, gU,
          pool3, iiH, latI, (const float*)0, PI, last?(u16*)0:PI, Si, I, 0);
    }
  }
}

// Round 12
// 861.290 us; speedup vs baseline: 1.0801x; 1.0354x over previous
//
#include <hip/hip_runtime.h>
#include <stdint.h>

#define LEAKY 0.1f
typedef unsigned short u16;
typedef unsigned int u32;
typedef unsigned char u8;
typedef short bf16x8 __attribute__((ext_vector_type(8)));
typedef float f32x4 __attribute__((ext_vector_type(4)));
typedef float f32x2 __attribute__((ext_vector_type(2)));

// ---------- bf16 helpers (storage = ushort) ----------
__device__ __forceinline__ float bflo(u32 u){ union{u32 i; float f;} c; c.i = u<<16; return c.f; }
__device__ __forceinline__ float bfhi(u32 u){ union{u32 i; float f;} c; c.i = u & 0xffff0000u; return c.f; }
__device__ __forceinline__ float bf2f(u16 v){ union{u32 i; float f;} c; c.i = ((u32)v)<<16; return c.f; }
__device__ __forceinline__ u16 f2bf(float f){
  union{float f; u32 i;} c; c.f = f;
  u32 r = (c.i + 0x7fffu + ((c.i>>16)&1u)) >> 16;
  return (u16)r;
}
__device__ __forceinline__ u32 pack2(float a, float b){ return (u32)f2bf(a) | ((u32)f2bf(b)<<16); }

// ---------- fp8 e4m3fn helpers ----------
// encode (soft, OCP e4m3 bias-7, RNE, clamp 448, never emits 0x7F/NaN)
__device__ __forceinline__ u32 f2fp8(float f){
  union{float f; u32 i;} c; c.f = f;
  u32 s = (c.i >> 24) & 0x80u;
  float a = fabsf(f); if (a > 448.f) a = 448.f;
  union{float f; u32 i;} d; d.f = a * 0x1p-120f;
  u32 u = d.i;
  u32 r = (u + 0x7FFFFu + ((u >> 20) & 1u)) >> 20;
  if (r > 0x7Eu) r = 0x7Eu;
  return s | r;
}
// decode: gfx950 HW packed convert (OCP e4m3fn), 1 VALU op for 2 values.
__device__ __forceinline__ f32x2 fp8x2_to_f(u32 b2){
  return __builtin_amdgcn_cvt_pk_f32_fp8((int)b2, false);
}

__device__ __forceinline__ void load8f(const float* p, float* v){
  const float4* q = (const float4*)p; float4 a = q[0], b = q[1];
  v[0]=a.x;v[1]=a.y;v[2]=a.z;v[3]=a.w;v[4]=b.x;v[5]=b.y;v[6]=b.z;v[7]=b.w;
}
__device__ __forceinline__ void load8h(const u16* p, float* v){
  uint4 u = *(const uint4*)p;
  v[0]=bflo(u.x);v[1]=bfhi(u.x);v[2]=bflo(u.y);v[3]=bfhi(u.y);
  v[4]=bflo(u.z);v[5]=bfhi(u.z);v[6]=bflo(u.w);v[7]=bfhi(u.w);
}
__device__ __forceinline__ void load4f(const float* p, float* v){
  float4 a = *(const float4*)p; v[0]=a.x;v[1]=a.y;v[2]=a.z;v[3]=a.w;
}
__device__ __forceinline__ void load4h(const u16* p, float* v){
  uint2 u = *(const uint2*)p;
  v[0]=bflo(u.x); v[1]=bfhi(u.x); v[2]=bflo(u.y); v[3]=bfhi(u.y);
}
__device__ __forceinline__ void store2bf(u16* p, float a, float b){
  *(u32*)p = pack2(a,b);
}
__device__ __forceinline__ void store4bf(u16* p, float a, float b, float c, float d){
  uint2 t; t.x = pack2(a,b); t.y = pack2(c,d);
  *(uint2*)p = t;
}

// ---------- misc: zero an int buffer ----------
__global__ __launch_bounds__(256) void zero_kernel(int* p, int n){
  int i = blockIdx.x*256 + threadIdx.x;
  if (i < n) p[i] = 0;
}

// ---------- stage W[128][128] fp32 -> LDS transposed bf16 Wt[n][k], stride 136 ----------
__device__ __forceinline__ void stageWt(const float* __restrict__ W, u16* Wt, int tid){
  const int n = tid & 127, khalf = tid >> 7;
#pragma unroll
  for (int g = 0; g < 16; ++g) {
    int k0 = khalf*64 + g*4;
    float w0 = W[(k0+0)*128 + n];
    float w1 = W[(k0+1)*128 + n];
    float w2 = W[(k0+2)*128 + n];
    float w3 = W[(k0+3)*128 + n];
    uint2 t; t.x = pack2(w0,w1); t.y = pack2(w2,w3);
    *(uint2*)&Wt[n*136 + k0] = t;
  }
}

// ---------- MFMA GEMM core: C[N,128] = A[N,128] @ W[128,128] ----------
// Output: bf16 (C) or fp8 e4m3 (C8, when non-null -- Y gather payload).
__device__ __forceinline__ void gemm_core(
    const float* __restrict__ Af, const u16* __restrict__ Ah,
    const float* __restrict__ W, u16* __restrict__ C, u8* __restrict__ C8,
    int N, int brow, u16* Wt, int tid)
{
  stageWt(W, Wt, tid);
  __syncthreads();

  const int w = tid >> 6, lane = tid & 63;
  const int m = lane & 15, quad = lane >> 4;
  const int rowBase = brow*64 + w*16;
  int arow = rowBase + m;
  if (arow >= N) arow = N-1;

  bf16x8 af[4];
  if (Ah) {
#pragma unroll
    for (int kt=0; kt<4; ++kt)
      af[kt] = *(const bf16x8*)(Ah + (size_t)arow*128 + kt*32 + quad*8);
  } else {
#pragma unroll
    for (int kt=0; kt<4; ++kt) {
      float v[8]; load8f(Af + (size_t)arow*128 + kt*32 + quad*8, v);
      bf16x8 t;
#pragma unroll
      for (int j=0;j<8;++j) t[j] = (short)f2bf(v[j]);
      af[kt] = t;
    }
  }

#pragma unroll
  for (int jt=0; jt<8; ++jt) {
    f32x4 acc = {0.f,0.f,0.f,0.f};
#pragma unroll
    for (int kt=0; kt<4; ++kt) {
      bf16x8 bf = *(const bf16x8*)&Wt[(jt*16+m)*136 + kt*32 + quad*8];
      acc = __builtin_amdgcn_mfma_f32_16x16x32_bf16(af[kt], bf, acc, 0, 0, 0);
    }
    const int col = jt*16 + m;
#pragma unroll
    for (int r=0;r<4;++r) {
      int rg = rowBase + quad*4 + r;
      if (rg < N) {
        if (C8) C8[(size_t)rg*128 + col] = (u8)f2fp8(acc[r]);
        else    C[(size_t)rg*128 + col] = f2bf(acc[r]);
      }
    }
  }
}

// dual GEMM: blocks [0,g1) -> side1, rest -> side2
__global__ __launch_bounds__(256) void gemm128_dual(
    const float* Af1, const u16* Ah1, const float* W1, u16* C1, u8* C81, int N1, int g1,
    const float* Af2, const u16* Ah2, const float* W2, u16* C2, u8* C82, int N2)
{
  __shared__ alignas(16) u16 Wt[128*136];
  const int b = blockIdx.x;
  if (b < g1) gemm_core(Af1, Ah1, W1, C1, C81, N1, b,      Wt, threadIdx.x);
  else        gemm_core(Af2, Ah2, W2, C2, C82, N2, b - g1, Wt, threadIdx.x);
}

// dual update kernel.
// r11 S-schedule: S traffic was 462MB (l0 write 154 + l1 RMW 308). Deferred:
// smode 2 = skip S entirely (l0 when L>=2); smode 3 = S = Base(fp32) + pv + ov
// (first S-writing layer; Base=uE/iE, pv=P_prev already loaded); smode 0 =
// S += ov (middle layers); smode 1 = S = pv + ov (L==1 only).
// Net for L=2: 462MB -> 231MB of S-related traffic.
__global__ __launch_bounds__(256) void update_dual(
    const u16* T1, const u16* Hy1, const float* W1,
    const float* PF1, const u16* PH1, u16* Po1, float* S1, const float* B1, int N1, int g1,
    const u16* T2, const u16* Hy2, const float* W2,
    const float* PF2, const u16* PH2, u16* Po2, float* S2, const float* B2, int N2, int smode)
{
  __shared__ alignas(16) char shmem[34816];  // union: Wt u16[128*136] | Gs f32[64*132]
  u16* Wt = (u16*)shmem;
  float* Gs = (float*)shmem;
  const int tid = threadIdx.x;
  const int b = blockIdx.x;

  const u16* T; const u16* Hy; const float* latW;
  const float* PrevF; const u16* PrevH; u16* Pout; float* S; const float* B; int N; int brow;
  if (b < g1) { T=T1; Hy=Hy1; latW=W1; PrevF=PF1; PrevH=PH1; Pout=Po1; S=S1; B=B1; N=N1; brow=b; }
  else        { T=T2; Hy=Hy2; latW=W2; PrevF=PF2; PrevH=PH2; Pout=Po2; S=S2; B=B2; N=N2; brow=b-g1; }

  stageWt(latW, Wt, tid);
  __syncthreads();

  const int w = tid >> 6, lane = tid & 63;
  const int m = lane & 15, quad = lane >> 4;
  const int rowBase = brow*64;
  int arow = rowBase + w*16 + m;
  if (arow >= N) arow = N-1;

  bf16x8 af[4];
#pragma unroll
  for (int kt=0; kt<4; ++kt)
    af[kt] = *(const bf16x8*)(Hy + (size_t)arow*128 + kt*32 + quad*8);

  f32x4 acc[8];
#pragma unroll
  for (int jt=0; jt<8; ++jt) {
    f32x4 a = {0.f,0.f,0.f,0.f};
#pragma unroll
    for (int kt=0; kt<4; ++kt) {
      bf16x8 bf = *(const bf16x8*)&Wt[(jt*16+m)*136 + kt*32 + quad*8];
      a = __builtin_amdgcn_mfma_f32_16x16x32_bf16(af[kt], bf, a, 0, 0, 0);
    }
    acc[jt] = a;
  }
  __syncthreads();   // all Wt reads done; reuse LDS as Gs
#pragma unroll
  for (int jt=0; jt<8; ++jt) {
#pragma unroll
    for (int r=0;r<4;++r) {
      float x = acc[jt][r];
      Gs[(w*16 + quad*4 + r)*132 + jt*16 + m] = x > 0.f ? x : LEAKY*x;
    }
  }
  __syncthreads();

  const int c4 = (tid & 31) * 4;
  const int r0 = tid >> 5;
#pragma unroll
  for (int ri=0; ri<8; ++ri) {
    int lr = r0 + ri*8;           // 0..63
    int n = rowBase + lr;
    if (n >= N) continue;
    size_t off = (size_t)n*128 + c4;
    float gv[4]; load4f(&Gs[lr*132 + c4], gv);
    float tv[4], pv[4], ov[4];
    load4h(T + off, tv);
    if (PrevH) load4h(PrevH + off, pv);
    else       load4f(PrevF + off, pv);
#pragma unroll
    for (int cc=0;cc<4;++cc) ov[cc] = gv[cc] + tv[cc] + pv[cc];
    if (Pout)
      store4bf(&Pout[off], ov[0],ov[1],ov[2],ov[3]);
    if (smode == 0) {
      float4 s = *(const float4*)&S[off];
      s.x += ov[0]; s.y += ov[1]; s.z += ov[2]; s.w += ov[3];
      *(float4*)&S[off] = s;
    } else if (smode == 1) {
      float4 s; s.x=pv[0]+ov[0]; s.y=pv[1]+ov[1]; s.z=pv[2]+ov[2]; s.w=pv[3]+ov[3];
      *(float4*)&S[off] = s;
    } else if (smode == 3) {
      float bv[4]; load4f(B + off, bv);
      float4 s; s.x=bv[0]+pv[0]+ov[0]; s.y=bv[1]+pv[1]+ov[1];
      s.z=bv[2]+pv[2]+ov[2]; s.w=bv[3]+pv[3]+ov[3];
      *(float4*)&S[off] = s;
    } // smode==2: no S write
  }
}

// ---------- hyper reduce v2 (MFMA): part[b] = Hy_chunk^T @ Lat_chunk ----------
#define RPAD 40
__global__ __launch_bounds__(256) void reduce_kernel(
    const u16* __restrict__ HyU, const u16* __restrict__ HyI,
    const float* __restrict__ LatUf, const u16* __restrict__ LatUh,
    const float* __restrict__ LatIf, const u16* __restrict__ LatIh,
    u16* __restrict__ part, int Nu, int Ni, int nbU)
{
  __shared__ alignas(16) u16 HsT[128*RPAD];
  __shared__ alignas(16) u16 LsT[128*RPAD];
  const int b = blockIdx.x;
  const u16* Hy; const float* Lf; const u16* Lh; int N, cstart;
  if (b < nbU) { Hy=HyU; Lf=LatUf; Lh=LatUh; N=Nu; cstart = b*256; }
  else         { Hy=HyI; Lf=LatIf; Lh=LatIh; N=Ni; cstart = (b-nbU)*256; }
  const int cend = (N < cstart+256) ? N : (cstart+256);
  const int tid = threadIdx.x;
  const int w = tid >> 6, lane = tid & 63;
  const int m = lane & 15, quad = lane >> 4;

  f32x4 acc[2][8];
#pragma unroll
  for (int a=0;a<2;++a)
#pragma unroll
    for (int c=0;c<8;++c) { acc[a][c][0]=0.f; acc[a][c][1]=0.f; acc[a][c][2]=0.f; acc[a][c][3]=0.f; }

  for (int t0 = cstart; t0 < cend; t0 += 32) {
#pragma unroll
    for (int it=0; it<2; ++it) {
      const int idx = it*256 + tid;
      const int n = idx & 31, h0 = (idx >> 5) * 8;
      const int row = t0 + n;
      u32 ax=0, ay=0, az=0, aw=0, lx=0, ly=0, lz=0, lw=0;
      if (row < cend) {
        uint4 uh = *(const uint4*)(Hy + (size_t)row*128 + h0);
        ax=uh.x; ay=uh.y; az=uh.z; aw=uh.w;
        if (Lh) {
          uint4 ul = *(const uint4*)(Lh + (size_t)row*128 + h0);
          lx=ul.x; ly=ul.y; lz=ul.z; lw=ul.w;
        } else {
          float v[8]; load8f(Lf + (size_t)row*128 + h0, v);
          lx = pack2(v[0],v[1]); ly = pack2(v[2],v[3]);
          lz = pack2(v[4],v[5]); lw = pack2(v[6],v[7]);
        }
      }
      u16* hp = &HsT[h0*RPAD + n];
      hp[0*RPAD]=(u16)ax; hp[1*RPAD]=(u16)(ax>>16);
      hp[2*RPAD]=(u16)ay; hp[3*RPAD]=(u16)(ay>>16);
      hp[4*RPAD]=(u16)az; hp[5*RPAD]=(u16)(az>>16);
      hp[6*RPAD]=(u16)aw; hp[7*RPAD]=(u16)(aw>>16);
      u16* lp = &LsT[h0*RPAD + n];
      lp[0*RPAD]=(u16)lx; lp[1*RPAD]=(u16)(lx>>16);
      lp[2*RPAD]=(u16)ly; lp[3*RPAD]=(u16)(ly>>16);
      lp[4*RPAD]=(u16)lz; lp[5*RPAD]=(u16)(lz>>16);
      lp[6*RPAD]=(u16)lw; lp[7*RPAD]=(u16)(lw>>16);
    }
    __syncthreads();
    bf16x8 a0 = *(const bf16x8*)&HsT[(w*32 +      m)*RPAD + quad*8];
    bf16x8 a1 = *(const bf16x8*)&HsT[(w*32 + 16 + m)*RPAD + quad*8];
#pragma unroll
    for (int td=0; td<8; ++td) {
      bf16x8 bfr = *(const bf16x8*)&LsT[(td*16 + m)*RPAD + quad*8];
      acc[0][td] = __builtin_amdgcn_mfma_f32_16x16x32_bf16(a0, bfr, acc[0][td], 0, 0, 0);
      acc[1][td] = __builtin_amdgcn_mfma_f32_16x16x32_bf16(a1, bfr, acc[1][td], 0, 0, 0);
    }
    __syncthreads();
  }
  u16* pb = part + (size_t)b*16384;
#pragma unroll
  for (int th=0; th<2; ++th) {
    const int h = w*32 + th*16 + quad*4;
#pragma unroll
    for (int td=0; td<8; ++td) {
      const int d = td*16 + m;
#pragma unroll
      for (int r=0;r<4;++r)
        pb[(size_t)(h+r)*128 + d] = f2bf(acc[th][td][r]);
    }
  }
}

// ---------- 2-stage partial reduction ----------
#define JS 16
__global__ __launch_bounds__(256) void reduce2a_kernel(
    const u16* __restrict__ part, float* __restrict__ Rp,
    int nbU, int nbI)
{
  const int e = blockIdx.x*256 + threadIdx.x;   // 0..16383
  const int side = blockIdx.z;
  const int nb = side ? nbI : nbU;
  const int per = (nb + JS - 1) / JS;
  const int j0 = blockIdx.y * per;
  int j1 = j0 + per; if (j1 > nb) j1 = nb;
  const u16* p = part + (side ? (size_t)nbU*16384 : 0) + e;
  float s = 0.f;
  for (int j=j0; j<j1; ++j) s += bf2f(p[(size_t)j*16384]);
  Rp[((size_t)side*JS + blockIdx.y)*16384 + e] = s;
}

__global__ __launch_bounds__(256) void reduce2b_kernel(
    const float* __restrict__ Rp, float* __restrict__ Ru, float* __restrict__ Ri)
{
  const int e = blockIdx.x*256 + threadIdx.x;   // 0..16383
  const int side = blockIdx.y;
  const float* p = Rp + (size_t)side*JS*16384 + e;
  float s = 0.f;
#pragma unroll
  for (int j=0; j<JS; ++j) s += p[(size_t)j*16384];
  if (side) Ri[e] = s; else Ru[e] = s;
}

// ---------- FC chain ----------
__global__ __launch_bounds__(128) void fc_kernel(
    const float* __restrict__ Ru, const float* __restrict__ Ri,
    const float* __restrict__ W3u, const float* __restrict__ W3i,
    float* __restrict__ latU, float* __restrict__ latI)
{
  __shared__ float cur[128];
  const int h = threadIdx.x;
  const int d = blockIdx.x;
  const int side = blockIdx.y;
  const float* R  = side ? Ri  : Ru;
  const float* W3 = side ? W3i : W3u;
  float* lat      = side ? latI : latU;
  float x = R[h*128 + d];
  cur[h] = x > 0.f ? x : LEAKY*x;
  __syncthreads();
  for (int s=0;s<3;++s) {
    const float* w = W3 + s*16384 + h;
    float val = 0.f;
#pragma unroll 8
    for (int hp=0; hp<128; ++hp) val = fmaf(cur[hp], w[hp*128], val);
    val = (val > 0.f ? val : 0.f) + cur[h];
    __syncthreads();
    cur[h] = val;
    __syncthreads();
  }
  lat[h*128+d] = cur[h];
}

// ---------- CSR-based SpMM: T[row,:] = relu( sum_e val_e * Y[idx_e,:] ) ----------
// STRUCTURAL FLOOR (r8-r11): transaction-rate-bound at 1 line/edge.
// MLP doubling (r8): null. FETCH halving via fp8 (r9-r11): -5%. 70us/dispatch.
__global__ __launch_bounds__(256) void spmm_kernel(
    const uint2* __restrict__ csr, const int* __restrict__ rowptr,
    const u8* __restrict__ Y, u16* __restrict__ T, int N, int Ncol, int E)
{
  const int lane = threadIdx.x & 63;
  const int row = blockIdx.x*4 + (threadIdx.x >> 6);
  if (row >= N) return;
  int e  = rowptr[row];
  int e1 = rowptr[row+1];
  if (e < 0) e = 0;
  if (e > E) e = E;
  if (e1 < e) e1 = e;
  if (e1 > E) e1 = E;
  const u32 cmax = (u32)(Ncol - 1);
  float a0=0.f, a1=0.f;
  const int c2 = lane*2;
  for (; e+4 <= e1; e += 4) {
    uint2 p0 = csr[e], p1 = csr[e+1], p2 = csr[e+2], p3 = csr[e+3];
    u32 i0 = p0.x < cmax ? p0.x : cmax;
    u32 i1 = p1.x < cmax ? p1.x : cmax;
    u32 i2 = p2.x < cmax ? p2.x : cmax;
    u32 i3 = p3.x < cmax ? p3.x : cmax;
    u32 y0 = *(const u16*)&Y[(size_t)i0*128 + c2];
    u32 y1 = *(const u16*)&Y[(size_t)i1*128 + c2];
    u32 y2 = *(const u16*)&Y[(size_t)i2*128 + c2];
    u32 y3 = *(const u16*)&Y[(size_t)i3*128 + c2];
    float v0 = __uint_as_float(p0.y), v1 = __uint_as_float(p1.y);
    float v2 = __uint_as_float(p2.y), v3 = __uint_as_float(p3.y);
    f32x2 d0 = fp8x2_to_f(y0), d1 = fp8x2_to_f(y1);
    f32x2 d2 = fp8x2_to_f(y2), d3 = fp8x2_to_f(y3);
    a0 = fmaf(v0, d0[0], a0); a1 = fmaf(v0, d0[1], a1);
    a0 = fmaf(v1, d1[0], a0); a1 = fmaf(v1, d1[1], a1);
    a0 = fmaf(v2, d2[0], a0); a1 = fmaf(v2, d2[1], a1);
    a0 = fmaf(v3, d3[0], a0); a1 = fmaf(v3, d3[1], a1);
  }
  for (; e < e1; ++e) {
    uint2 p0 = csr[e];
    u32 i0 = p0.x < cmax ? p0.x : cmax;
    u32 y0 = *(const u16*)&Y[(size_t)i0*128 + c2];
    float v0 = __uint_as_float(p0.y);
    f32x2 d0 = fp8x2_to_f(y0);
    a0 = fmaf(v0, d0[0], a0); a1 = fmaf(v0, d0[1], a1);
  }
  store2bf(&T[(size_t)row*128 + c2], a0 > 0.f ? a0 : 0.f, a1 > 0.f ? a1 : 0.f);
}

// ---------- CSR build ----------
#define HCB 32768              // bins per chunk (u16-packed)
#define HWORDS (HCB/2)         // 16384 u32 words = 64KB
#define HS  64                 // edge slices
__global__ __launch_bounds__(256) void hist_part_kernel(
    const int* __restrict__ rows, const int* __restrict__ cols,
    u32* __restrict__ part, int E, int cU)
{
  __shared__ alignas(16) u32 h[HWORDS];
  const int c = blockIdx.x, s = blockIdx.y;
  const int* key = (c < cU) ? rows : cols;
  const u32 lo = (u32)((c < cU ? c : c - cU) * HCB);
  {
    uint4 z; z.x=0; z.y=0; z.z=0; z.w=0;
    uint4* h4 = (uint4*)h;
    for (int i = threadIdx.x; i < HWORDS/4; i += 256) h4[i] = z;
  }
  __syncthreads();
  int per = (E + HS - 1) / HS;
  per = (per + 3) & ~3;                      // multiple of 4: int4-aligned slices
  const int e0 = s*per;
  const int e1 = (E < e0+per) ? E : (e0+per);
  if (e0 < e1) {
    const int4* kp = (const int4*)(key + e0);
    const int nv = (e1 - e0) >> 2;
    for (int i = threadIdx.x; i < nv; i += 256) {
      int4 kv = kp[i];
      u32 k0=(u32)kv.x-lo, k1=(u32)kv.y-lo, k2=(u32)kv.z-lo, k3=(u32)kv.w-lo;
      if (k0 < (u32)HCB) atomicAdd(&h[k0>>1], 1u << ((k0&1)<<4));
      if (k1 < (u32)HCB) atomicAdd(&h[k1>>1], 1u << ((k1&1)<<4));
      if (k2 < (u32)HCB) atomicAdd(&h[k2>>1], 1u << ((k2&1)<<4));
      if (k3 < (u32)HCB) atomicAdd(&h[k3>>1], 1u << ((k3&1)<<4));
    }
    for (int e = e0 + (nv<<2) + threadIdx.x; e < e1; e += 256) {
      u32 k = (u32)key[e] - lo;
      if (k < (u32)HCB) atomicAdd(&h[k>>1], 1u << ((k&1)<<4));
    }
  }
  __syncthreads();
  uint4* dst = (uint4*)(part + (size_t)(c*HS + s) * HWORDS);
  const uint4* h4 = (const uint4*)h;
  for (int i = threadIdx.x; i < HWORDS/4; i += 256) dst[i] = h4[i];
}

__global__ __launch_bounds__(256) void scan_local_kernel(
    const u32* __restrict__ part,
    int* rpU, int* rpI, int* bsU, int* bsI, int Nu, int Ni, int cU)
{
  const int side = blockIdx.y;
  const int Nn = side ? Ni : Nu;
  int* rp = side ? rpI : rpU;
  int* bs = side ? bsI : bsU;
  const int nb = (Nn + 4095) >> 12;
  if ((int)blockIdx.x >= nb) return;
  __shared__ int sa[256], sb[256];
  const int tid = threadIdx.x;
  const int base = blockIdx.x*4096 + tid*16;   // 16 bins; never crosses a 32768 chunk boundary
  int v[16];
#pragma unroll
  for (int q=0;q<16;++q) v[q]=0;
  {
    const int gc = (side ? cU : 0) + (base >> 15);       // global chunk
    const int w0 = (base & (HCB-1)) >> 1;                // first packed word (8 words = 16 bins)
    const u32* ps = part + (size_t)gc*HS*HWORDS + w0;
    for (int s=0; s<HS; ++s) {
      const uint4* pw = (const uint4*)(ps + (size_t)s*HWORDS);
      uint4 a = pw[0], b = pw[1];
      v[0]+= (int)(a.x&0xffffu); v[1]+= (int)(a.x>>16);
      v[2]+= (int)(a.y&0xffffu); v[3]+= (int)(a.y>>16);
      v[4]+= (int)(a.z&0xffffu); v[5]+= (int)(a.z>>16);
      v[6]+= (int)(a.w&0xffffu); v[7]+= (int)(a.w>>16);
      v[8]+= (int)(b.x&0xffffu); v[9]+= (int)(b.x>>16);
      v[10]+=(int)(b.y&0xffffu); v[11]+=(int)(b.y>>16);
      v[12]+=(int)(b.z&0xffffu); v[13]+=(int)(b.z>>16);
      v[14]+=(int)(b.w&0xffffu); v[15]+=(int)(b.w>>16);
    }
  }
  int sum = 0;
#pragma unroll
  for (int q=0;q<16;++q) sum += v[q];
  sa[tid] = sum; __syncthreads();
  int* src = sa; int* dst = sb;
  for (int off=1; off<256; off<<=1) {
    int x = src[tid] + ((tid>=off) ? src[tid-off] : 0);
    dst[tid] = x;
    __syncthreads();
    int* t = src; src = dst; dst = t;
  }
  const int incl = src[tid];
  int run = incl - sum;  // exclusive
#pragma unroll
  for (int q=0;q<16;++q){ int idx=base+q; if (idx<Nn) rp[idx]=run; run+=v[q]; }
  if (tid==255) bs[blockIdx.x] = incl;
}

__global__ void scan_blocks_kernel(int* bsU, int* bsI, int* rpU, int* rpI, int Nu, int Ni)
{
  if (threadIdx.x != 0) return;
  const int side = blockIdx.y;
  int* bs = side?bsI:bsU; int* rp = side?rpI:rpU;
  const int Nn = side?Ni:Nu;
  const int nb = (Nn+4095)>>12;
  int run = 0;
  for (int b=0;b<nb;++b){ int t=bs[b]; bs[b]=run; run+=t; }
  rp[Nn] = run;
}

__global__ __launch_bounds__(256) void scan_add_kernel(
    const int* bsU, const int* bsI, int* rpU, int* rpI, int Nu, int Ni)
{
  const int side = blockIdx.y;
  const int Nn = side?Ni:Nu;
  const int* bs = side?bsI:bsU;
  int* rp = side?rpI:rpU;
  const int nb = (Nn+4095)>>12;
  if ((int)blockIdx.x >= nb) return;
  const int add = bs[blockIdx.x];
  const int base = blockIdx.x*4096 + threadIdx.x*16;
#pragma unroll
  for (int q=0;q<16;++q){ int idx=base+q; if (idx<Nn) rp[idx]+=add; }
}

// scatter (r8/r9 form): both sides window on c.
__global__ __launch_bounds__(256) void scatter_kernel(
    const int* __restrict__ rows, const int* __restrict__ cols, const float* __restrict__ vals,
    const int* __restrict__ rpU, const int* __restrict__ rpI,
    int* curU, int* curI, uint2* csrU, uint2* csrI, int E, int Nu, int Ni,
    int u0, int u1, int i0w, int i1w)
{
  (void)u0; (void)u1;
  int e = blockIdx.x*256 + threadIdx.x;
  if (e >= E) return;
  int r = rows[e], c = cols[e];
  if ((unsigned)r < (unsigned)Nu && (unsigned)c < (unsigned)Ni) {
    u32 vb = __float_as_uint(vals[e]);
    if (c >= i0w && c < i1w) {
      int su = rpU[r] + atomicAdd(&curU[r], 1);
      if ((unsigned)su < (unsigned)E) { uint2 t; t.x=(u32)c; t.y=vb; csrU[su]=t; }
      int si = rpI[c] + atomicAdd(&curI[c], 1);
      if ((unsigned)si < (unsigned)E) { uint2 t; t.x=(u32)r; t.y=vb; csrI[si]=t; }
    }
  }
}

// ---------- host ----------
extern "C" void kernel_launch(void* const* d_in, const int* in_sizes, int n_in,
                              void* d_out, int out_size, void* d_ws, size_t ws_size,
                              hipStream_t stream)
{
  const float* uE     = (const float*)d_in[0];
  const float* iE     = (const float*)d_in[1];
  const float* uhyper = (const float*)d_in[2];
  const float* ihyper = (const float*)d_in[3];
  const float* vals   = (const float*)d_in[4];
  const float* WhU    = (const float*)d_in[5];  // [L,3,128,128]
  const float* WhI    = (const float*)d_in[6];
  const float* WgU    = (const float*)d_in[7];  // [L,128,128]
  const float* WgI    = (const float*)d_in[8];
  const int*   rows   = (const int*)d_in[9];
  const int*   cols   = (const int*)d_in[10];
  const int U = in_sizes[0]/128;
  const int I = in_sizes[1]/128;
  const int E = in_sizes[4];
  const int L = in_sizes[7]/(128*128);
  (void)n_in; (void)out_size;

  float* Su = (float*)d_out;
  float* Si = Su + (size_t)U*128;

  char* base0 = (char*)d_ws;
  u16* uuH; u16* iiH; u16* PU; u16* PI; u16* YU; u16* TU; u16* pool3;
  uint2* csrU; uint2* csrI; int* rpU; int* rpI; int* cntU; int* cntI;
  int* bsU; int* bsI; float* Ru; float* Ri; float* latU; float* latI; float* Rp;
  {
    size_t off = 0;
    #define ALLOC(var, type, bytes) var = (type)(base0 + off); off = (off + (bytes) + 255) & ~(size_t)255;
    ALLOC(uuH,  u16*, (size_t)U*128*2)
    ALLOC(iiH,  u16*, (size_t)I*128*2)
    ALLOC(PU,   u16*, (size_t)U*128*2)
    ALLOC(PI,   u16*, (size_t)I*128*2)
    ALLOC(YU,   u16*, (size_t)U*128*2)      // Y_U (fp8, half used); reduce partials later
    ALLOC(TU,   u16*, (size_t)U*128*2)
    ALLOC(pool3,u16*, (size_t)I*128*2)      // Y_I (fp8) then T_I (bf16)
    ALLOC(csrU, uint2*, (size_t)E*8)
    ALLOC(csrI, uint2*, (size_t)E*8)
    ALLOC(rpU,  int*, (size_t)(U+1)*4)
    ALLOC(rpI,  int*, (size_t)(I+1)*4)
    ALLOC(cntU, int*, (size_t)U*4)
    ALLOC(cntI, int*, (size_t)I*4)
    ALLOC(bsU,  int*, 64*4)
    ALLOC(bsI,  int*, 64*4)
    ALLOC(Ru,   float*, 16384*4)
    ALLOC(Ri,   float*, 16384*4)
    ALLOC(latU, float*, 16384*4)
    ALLOC(latI, float*, 16384*4)
    ALLOC(Rp,   float*, (size_t)2*JS*16384*4)   // 2-stage reduce partials (2MB)
    #undef ALLOC
    if (off > ws_size) return;   // clean bail, graph-safe
  }
  const int cntN = (int)(((size_t)((char*)bsU - (char*)cntU)) / 4);

  const int nbU = (U+4095)>>12, nbI = (I+4095)>>12;
  const int nbMax = nbU > nbI ? nbU : nbI;
  const int rbU = (U+255)>>8, rbI = (I+255)>>8;   // reduce chunks (256 rows)
  const int gU = (U+63)/64, gI = (I+63)/64;        // MFMA gemm/update grids
  const int cU = (U + HCB-1)/HCB, cI = (I + HCB-1)/HCB;  // hist bin-chunks

  u32* hpart = (u32*)csrU;
  u8* Y8u = (u8*)YU;       // fp8 Y_U
  u8* Y8i = (u8*)pool3;    // fp8 Y_I

  // --- CSR build (both directions) ---
  hist_part_kernel<<<dim3(cU+cI, HS), 256, 0, stream>>>(rows, cols, hpart, E, cU);
  scan_local_kernel<<<dim3(nbMax,2), 256, 0, stream>>>(hpart,rpU,rpI,bsU,bsI,U,I,cU);
  scan_blocks_kernel<<<dim3(1,2), 64, 0, stream>>>(bsU,bsI,rpU,rpI,U,I);
  scan_add_kernel<<<dim3(nbMax,2), 256, 0, stream>>>(bsU,bsI,rpU,rpI,U,I);
  zero_kernel<<<(cntN+255)/256, 256, 0, stream>>>(cntU, cntN);
  for (int wnd = 0; wnd < 4; ++wnd) {
    int u0 = (int)(((long long)wnd   * U) / 4);
    int u1 = (int)(((long long)(wnd+1) * U) / 4);
    int i0w = (int)(((long long)wnd   * I) / 4);
    int i1w = (int)(((long long)(wnd+1) * I) / 4);
    scatter_kernel<<<(E+255)/256, 256, 0, stream>>>(
        rows, cols, vals, rpU, rpI, cntU, cntI, csrU, csrI, E, U, I,
        u0, u1, i0w, i1w);
  }

  // --- hyper embeddings (merged U+I, bf16 out) ---
  gemm128_dual<<<gU+gI, 256, 0, stream>>>(uE, (const u16*)0, uhyper, uuH, (u8*)0, U, gU,
                                          iE, (const u16*)0, ihyper, iiH, (u8*)0, I);

  for (int l=0; l<L; ++l) {
    const float* wgu = WgU + (size_t)l*16384;
    const float* wgi = WgI + (size_t)l*16384;
    const float* whu = WhU + (size_t)l*3*16384;
    const float* whi = WhI + (size_t)l*3*16384;
    const bool last = (l == L-1);
    // S schedule: l==0 && L>1 -> skip(2); l==0 && L==1 -> init2(1);
    // first S-writer (l==1): init3-with-base(3); later: accum(0).
    int smode;
    if (l == 0) smode = (L == 1) ? 1 : 2;
    else if (l == 1) smode = 3;
    else smode = 0;
    if (l == 0) {
      // Y_I = iE@WgU -> Y8i(fp8) ; Y_U = uE@WgI -> Y8u(fp8)  (merged)
      gemm128_dual<<<gI+gU, 256, 0, stream>>>(iE, (const u16*)0, wgu, (u16*)0, Y8i, I, gI,
                                              uE, (const u16*)0, wgi, (u16*)0, Y8u, U);
      spmm_kernel<<<(U+3)/4, 256, 0, stream>>>(csrU, rpU, Y8i, TU, U, I, E);   // T_U
      spmm_kernel<<<(I+3)/4, 256, 0, stream>>>(csrI, rpI, Y8u, pool3, I, U, E); // T_I (pool3 reused)
      reduce_kernel<<<rbU+rbI, 256, 0, stream>>>(uuH,iiH, uE,(const u16*)0, iE,(const u16*)0, YU,U,I,rbU);
      reduce2a_kernel<<<dim3(64,JS,2), 256, 0, stream>>>(YU, Rp, rbU, rbI);
      reduce2b_kernel<<<dim3(64,2), 256, 0, stream>>>(Rp, Ru, Ri);
      fc_kernel<<<dim3(128,2), 128, 0, stream>>>(Ru,Ri,whu,whi,latU,latI);
      update_dual<<<gU+gI, 256, 0, stream>>>(
          TU,    uuH, latU, uE, (const u16*)0, PU, Su, uE, U, gU,
          pool3, iiH, latI, iE, (const u16*)0, PI, Si, iE, I, smode);
    } else {
      gemm128_dual<<<gI+gU, 256, 0, stream>>>((const float*)0, PI, wgu, (u16*)0, Y8i, I, gI,
                                              (const float*)0, PU, wgi, (u16*)0, Y8u, U);
      spmm_kernel<<<(U+3)/4, 256, 0, stream>>>(csrU, rpU, Y8i, TU, U, I, E);
      spmm_kernel<<<(I+3)/4, 256, 0, stream>>>(csrI, rpI, Y8u, pool3, I, U, E);
      reduce_kernel<<<rbU+rbI, 256, 0, stream>>>(uuH,iiH, (const float*)0,PU, (const float*)0,PI, YU,U,I,rbU);
      reduce2a_kernel<<<dim3(64,JS,2), 256, 0, stream>>>(YU, Rp, rbU, rbI);
      reduce2b_kernel<<<dim3(64,2), 256, 0, stream>>>(Rp, Ru, Ri);
      fc_kernel<<<dim3(128,2), 128, 0, stream>>>(Ru,Ri,whu,whi,latU,latI);
      update_dual<<<gU+gI, 256, 0, stream>>>(
          TU,    uuH, latU, (const float*)0, PU, last?(u16*)0:PU, Su, uE, U, gU,
          pool3, iiH, latI, (const float*)0, PI, last?(u16*)0:PI, Si, iE, I, smode);
    }
  }
}